// Round 4
// baseline (681.382 us; speedup 1.0000x reference)
//
#include <hip/hip_runtime.h>
#include <cstdint>
#include <cstddef>

// ---------------- constants ----------------
#define L_SEQ   2048
#define NROWS   16384            // B*L = 8*2048
#define D_MODEL 512
#define D_INNER 1024
#define D_STATE 64
#define NHEADS  16
#define CONV_DIM 1152
#define D_IN_PROJ 2192
#define D_FF 2048
#define EPS 1e-6f

typedef __bf16 bf16_t;
typedef __bf16 bf16x8 __attribute__((ext_vector_type(8)));
typedef __bf16 bf16x4 __attribute__((ext_vector_type(4)));
typedef float  f32x4  __attribute__((ext_vector_type(4)));

// workspace layout (bytes)
#define OFF_WT_IN    0ull                       // 2192*512 bf16  = 2,244,608
#define OFF_WT_OUT   2244608ull                 // 512*1024 bf16  = 1,048,576
#define OFF_W1T      3293184ull                 // 2048*512 bf16  = 2,097,152
#define OFF_W2T      5390336ull                 // 512*2048 bf16  = 2,097,152
#define OFF_U        7487488ull                 // 16384*512 bf16 (u_bf; reused: la_buf during scan, h_bf later)
#define OFF_XBC_RAW  24264704ull                // 16384*1152 f32 (xbc_raw; reused: Tc/S_buf during scan, gelu bf16 later)
#define OFF_XBC_CONV 99762176ull                // 16384*1152 f32
#define OFF_Y2       175259648ull               // 2*16384*1024 bf16 = 67,108,864
#define OFF_YN       242368512ull               // 16384*1024 bf16 = 33,554,432
// total ~276 MB

// ---------------- helpers ----------------
__device__ __forceinline__ void gl_lds16(const void* g, void* s) {
  __builtin_amdgcn_global_load_lds(
      (__attribute__((address_space(1))) void*)(void*)g,
      (__attribute__((address_space(3))) void*)s, 16, 0, 0);
}

__device__ __forceinline__ float block_sum256(float v, float* red) {
#pragma unroll
  for (int o = 32; o > 0; o >>= 1) v += __shfl_xor(v, o, 64);
  int w = threadIdx.x >> 6;
  if ((threadIdx.x & 63) == 0) red[w] = v;
  __syncthreads();
  return red[0] + red[1] + red[2] + red[3];
}

__device__ __forceinline__ float softplus_f(float x) {
  return (x > 20.f) ? x : log1pf(expf(x));
}
__device__ __forceinline__ float silu_f(float x) {
  return x / (1.f + expf(-x));
}
__device__ __forceinline__ float gelu_tanh_f(float x) {
  float x3 = x * x * x;
  return 0.5f * x * (1.f + tanhf(0.7978845608f * (x + 0.044715f * x3)));
}

// ---------------- weight prep: fp32 -> bf16, transposed ----------------
__global__ __launch_bounds__(256) void prep_weights_kernel(
    const float* __restrict__ W_in, const float* __restrict__ W_out,
    const float* __restrict__ W1, const float* __restrict__ W2,
    bf16_t* __restrict__ wt_in, bf16_t* __restrict__ wt_out,
    bf16_t* __restrict__ w1t, bf16_t* __restrict__ w2t) {
  const int S1 = D_IN_PROJ * 512;   // 1122304
  const int S2 = 512 * 1024;        // 524288
  const int S3 = 2048 * 512;        // 1048576
  const int S4 = 512 * 2048;        // 1048576
  const int total = S1 + S2 + S3 + S4;
  for (int i = blockIdx.x * 256 + threadIdx.x; i < total; i += gridDim.x * 256) {
    if (i < S1) {
      int n = i / 512, k = i - n * 512;
      wt_in[i] = (bf16_t)W_in[k * D_IN_PROJ + n];
    } else if (i < S1 + S2) {
      int j = i - S1; int n = j >> 10, k = j & 1023;
      wt_out[j] = (bf16_t)W_out[k * 512 + n];
    } else if (i < S1 + S2 + S3) {
      int j = i - S1 - S2; int n = j >> 9, k = j & 511;
      w1t[j] = (bf16_t)W1[k * 2048 + n];
    } else {
      int j = i - S1 - S2 - S3; int n = j >> 11, k = j & 2047;
      w2t[j] = (bf16_t)W2[k * 512 + n];
    }
  }
}

// ---------------- rmsnorm of masked input -> bf16 ----------------
__global__ __launch_bounds__(256) void rmsnorm_in_kernel(
    const float* __restrict__ x, const float* __restrict__ mask,
    bf16_t* __restrict__ u) {
  __shared__ float red[4];
  int row = blockIdx.x;
  float mk = mask[row];
  const float* xr = x + (size_t)row * 512;
  float v0 = xr[threadIdx.x] * mk;
  float v1 = xr[threadIdx.x + 256] * mk;
  float ss = block_sum256(v0 * v0 + v1 * v1, red);
  float r = rsqrtf(ss * (1.f / 512.f) + EPS);
  bf16_t* ur = u + (size_t)row * 512;
  ur[threadIdx.x] = (bf16_t)(v0 * r);
  ur[threadIdx.x + 256] = (bf16_t)(v1 * r);
}

// ---------------- rmsnorm of 2*m -> bf16 ----------------
__global__ __launch_bounds__(256) void rmsnorm2_kernel(
    const float* __restrict__ m, bf16_t* __restrict__ h) {
  __shared__ float red[4];
  int row = blockIdx.x;
  const float* mr = m + (size_t)row * 512;
  float v0 = 2.f * mr[threadIdx.x];
  float v1 = 2.f * mr[threadIdx.x + 256];
  float ss = block_sum256(v0 * v0 + v1 * v1, red);
  float r = rsqrtf(ss * (1.f / 512.f) + EPS);
  bf16_t* hr = h + (size_t)row * 512;
  hr[threadIdx.x] = (bf16_t)(v0 * r);
  hr[threadIdx.x + 256] = (bf16_t)(v1 * r);
}

// ---------------- MFMA GEMM: C[M,N] = A[M,K](bf16) @ Bt[N,K](bf16)^T ----------------
// v4: T3-minimum 2-phase double buffer (m248 recipe): STAGE(next) issued BEFORE compute(cur),
//     single __syncthreads() AFTER compute (drain overlaps load latency with ds_read+MFMA).
//     Swizzle reverted (R3: bank-conflict counter identical with/without); scalar epilogue (R1-proven).
template <int EPI>
__global__ __launch_bounds__(256, 2) void gemm_kernel(
    const bf16_t* __restrict__ A, const bf16_t* __restrict__ Bt,
    int M, int N, int K,
    float* __restrict__ o0, float* __restrict__ o1, float* __restrict__ o2,
    bf16_t* __restrict__ ob, const float* __restrict__ bias,
    const float* __restrict__ extra) {
  __shared__ bf16_t As[2][128 * 32];
  __shared__ bf16_t Bs[2][128 * 32];
  const int tid = threadIdx.x;
  const int lane = tid & 63;
  const int w = tid >> 6;
  const int tileM = blockIdx.y * 128;
  const int tileN = blockIdx.x * 128;

  f32x4 acc[4][4] = {};

  const int wm = (w >> 1) * 64;
  const int wn = (w & 1) * 64;
  const int fr = lane & 15;
  const int fk = (lane >> 4) * 8;

  const int rsub = lane >> 2;                  // row-within-16 of this lane's 16B chunk
  const int cb   = (lane & 3) * 16;            // byte col within 64B row

  auto stage = [&](int buf, int k0) {
#pragma unroll
    for (int i = 0; i < 2; ++i) {
      int rloc = w * 32 + i * 16 + rsub;
      const char* ga = (const char*)(A + (size_t)(tileM + rloc) * K + k0) + cb;
      gl_lds16(ga, (void*)&As[buf][(w * 32 + i * 16) * 32]);
      int rn = tileN + rloc;
      if (rn >= N) rn = N - 1;
      const char* gb = (const char*)(Bt + (size_t)rn * K + k0) + cb;
      gl_lds16(gb, (void*)&Bs[buf][(w * 32 + i * 16) * 32]);
    }
  };

  const int nt = K >> 5;
  stage(0, 0);
  __syncthreads();          // vmcnt(0) drain: buf0 landed for all waves
  int cur = 0;
  for (int t = 0; t < nt; ++t) {
    if (t + 1 < nt) stage(cur ^ 1, (t + 1) << 5);   // issue next-tile loads FIRST

    bf16x8 av[4], bv[4];
#pragma unroll
    for (int i = 0; i < 4; ++i)
      av[i] = *(const bf16x8*)&As[cur][(wm + i * 16 + fr) * 32 + fk];
#pragma unroll
    for (int j = 0; j < 4; ++j)
      bv[j] = *(const bf16x8*)&Bs[cur][(wn + j * 16 + fr) * 32 + fk];
#pragma unroll
    for (int i = 0; i < 4; ++i)
#pragma unroll
      for (int j = 0; j < 4; ++j)
        acc[i][j] = __builtin_amdgcn_mfma_f32_16x16x32_bf16(av[i], bv[j], acc[i][j], 0, 0, 0);

    __syncthreads();        // lgkm (reads of cur done) + vmcnt(0) (next tile landed) + barrier
    cur ^= 1;
  }

  // -------- epilogue (R1-proven scalar form) --------
  const int cn = lane & 15;
  const int r0 = (lane >> 4) * 4;
#pragma unroll
  for (int i = 0; i < 4; ++i) {
#pragma unroll
    for (int j = 0; j < 4; ++j) {
      int gn = tileN + wn + j * 16 + cn;
      if (gn >= N) continue;
#pragma unroll
      for (int r = 0; r < 4; ++r) {
        int gm = tileM + wm + i * 16 + r0 + r;
        float v = acc[i][j][r];
        if (EPI == 0) {
          o0[(size_t)gm * N + gn] = v;
        } else if (EPI == 1) {
          if (gn < D_INNER) {
            o0[(size_t)gm * D_INNER + gn] = v;                       // z
          } else if (gn < D_INNER + CONV_DIM) {
            o1[(size_t)gm * CONV_DIM + (gn - D_INNER)] = v;          // xBC raw
          } else {
            int hh = gn - (D_INNER + CONV_DIM);
            o2[(size_t)gm * NHEADS + hh] = softplus_f(v + bias[hh]); // dt
          }
        } else if (EPI == 2) {
          ob[(size_t)gm * N + gn] = (bf16_t)gelu_tanh_f(v + bias[gn]);
        } else if (EPI == 3) {
          o0[(size_t)gm * N + gn] = v + bias[gn] + 2.f * extra[(size_t)gm * N + gn];
        }
      }
    }
  }
}

// ---------------- causal conv1d (k=4) + silu + mask ----------------
__global__ __launch_bounds__(384) void conv_silu_kernel(
    const float* __restrict__ xbc_raw, const float* __restrict__ conv_w,
    const float* __restrict__ conv_b, const float* __restrict__ mask,
    float* __restrict__ xbc_conv) {
  int row = blockIdx.x;
  int t = row & (L_SEQ - 1);
  float mk = mask[row];
#pragma unroll
  for (int k = 0; k < 3; ++k) {
    int c = threadIdx.x + k * 384;
    float4 wv = ((const float4*)conv_w)[c];   // conv_w[c][0..3]
    float acc = conv_b[c];
    if (t >= 3) acc += wv.x * xbc_raw[(size_t)(row - 3) * CONV_DIM + c];
    if (t >= 2) acc += wv.y * xbc_raw[(size_t)(row - 2) * CONV_DIM + c];
    if (t >= 1) acc += wv.z * xbc_raw[(size_t)(row - 1) * CONV_DIM + c];
    acc += wv.w * xbc_raw[(size_t)row * CONV_DIM + c];
    xbc_conv[(size_t)row * CONV_DIM + c] = silu_f(acc) * mk;
  }
}

// ================= SSD chunked scan =================
// Chunk T=64. K1 (parallel, 8192 blocks): la prefix, Gt=B@C^T, M-mask, Y_intra=M@X -> y2,
//   Tc = X^T@(w.B) -> Tc_buf, la -> la_buf.
// K2a (parallel over state elems): in-place over Tc_buf, replace Tc_c with S_c
//   (state ENTERING chunk c): S=0; for c: {store S; S = exp(la63_c)*S + Tc_c}.
// K2b (parallel, 2048 blocks): Y_state[t,p] = exp(la[t]) * sum_n C[t,n]*S_c[p,n], RMW y2.

// ---------------- K1: per-chunk parallel kernel (8192 blocks) ----------------
__global__ __launch_bounds__(256) void scan_chunk_kernel(
    const float* __restrict__ xbc, const float* __restrict__ dt_all,
    const float* __restrict__ A_log,
    bf16_t* __restrict__ y2, bf16_t* __restrict__ Tc_buf,
    float* __restrict__ la_buf) {
  const int bid = blockIdx.x;
  const int c = bid & 31, h = (bid >> 5) & 15, b = (bid >> 9) & 7, dir = bid >> 12;
  const float A_h = -expf(A_log[h]);
  const int tid = threadIdx.x, w = tid >> 6, lane = tid & 63;
  const int fr = lane & 15, fk = (lane >> 4) * 8;

  __shared__ __align__(16) bf16_t sB[64][72];    // B rows [s][n]; aliased as M[t][s] later
  __shared__ __align__(16) bf16_t sC[64][72];    // C rows [t][n]
  __shared__ __align__(16) bf16_t sXt[64][72];   // X^T [p][s]
  __shared__ __align__(16) bf16_t sBwt[64][72];  // (w.B)^T [n][s]
  __shared__ float sLa[64], sDt[64], sW[64];

  const size_t base = (size_t)b * L_SEQ;
#define ROWOF(i) (base + (size_t)(dir ? (L_SEQ - 1 - (c * 64 + (i))) : (c * 64 + (i))))

  if (tid < 64) sDt[tid] = dt_all[ROWOF(tid) * NHEADS + h];

  float bB[16];
#pragma unroll
  for (int r = 0; r < 16; ++r) {
    int i = w * 16 + r;
    const float* src = xbc + ROWOF(i) * CONV_DIM;
    float xv = src[h * 64 + lane];
    float bv = src[D_INNER + lane];
    float cv = src[D_INNER + D_STATE + lane];
    bB[r] = bv;
    sB[i][lane] = (bf16_t)bv;
    sC[i][lane] = (bf16_t)cv;
    sXt[lane][i] = (bf16_t)xv;
  }
  __syncthreads();

  if (w == 0) {
    float v = sDt[lane] * A_h;
#pragma unroll
    for (int d = 1; d < 64; d <<= 1) {
      float o = __shfl_up(v, d, 64);
      if (lane >= d) v += o;
    }
    sLa[lane] = v;
    float la63 = __shfl(v, 63, 64);
    sW[lane] = __expf(la63 - v) * sDt[lane];
  }
  __syncthreads();

  // weighted-transposed B, and la out
#pragma unroll
  for (int r = 0; r < 16; ++r) {
    int i = w * 16 + r;
    sBwt[lane][i] = (bf16_t)(bB[r] * sW[i]);
  }
  if (tid < 64) la_buf[(size_t)bid * 64 + tid] = sLa[tid];

  // GEMM1: Gt[s, t-tile w] = B @ C^T (skip all-zero upper s-tiles: mi > w)
  f32x4 acc1[4] = {};
#pragma unroll
  for (int k0 = 0; k0 < 64; k0 += 32) {
    bf16x8 bv = *(const bf16x8*)&sC[w * 16 + fr][k0 + fk];
#pragma unroll
    for (int mi = 0; mi < 4; ++mi) {
      if (mi <= w) {
        bf16x8 av = *(const bf16x8*)&sB[mi * 16 + fr][k0 + fk];
        acc1[mi] = __builtin_amdgcn_mfma_f32_16x16x32_bf16(av, bv, acc1[mi], 0, 0, 0);
      }
    }
  }
  __syncthreads();   // GEMM1 reads done (sB can be overwritten); sBwt visible

  // build M[t][s] into sB alias
  {
    bf16_t (*sM)[72] = sB;
    float la_t = sLa[w * 16 + fr];
    int t = w * 16 + fr;
#pragma unroll
    for (int mi = 0; mi < 4; ++mi) {
#pragma unroll
      for (int r = 0; r < 4; ++r) {
        int s = mi * 16 + (lane >> 4) * 4 + r;
        float mv = 0.f;
        if (s <= t) mv = acc1[mi][r] * __expf(la_t - sLa[s]) * sDt[s];
        sM[t][s] = (bf16_t)mv;
      }
    }
  }

  // GEMM3: Tc[p, n-tile w] = X^T @ Bw  (independent of M writes)
  f32x4 acc3[4] = {};
#pragma unroll
  for (int k0 = 0; k0 < 64; k0 += 32) {
    bf16x8 bv = *(const bf16x8*)&sBwt[w * 16 + fr][k0 + fk];
#pragma unroll
    for (int mi = 0; mi < 4; ++mi) {
      bf16x8 av = *(const bf16x8*)&sXt[mi * 16 + fr][k0 + fk];
      acc3[mi] = __builtin_amdgcn_mfma_f32_16x16x32_bf16(av, bv, acc3[mi], 0, 0, 0);
    }
  }
  __syncthreads();   // M visible

  // GEMM2: Y[t, p-tile w] = M @ X
  f32x4 acc2[4] = {};
  {
    bf16_t (*sM)[72] = sB;
#pragma unroll
    for (int k0 = 0; k0 < 64; k0 += 32) {
      bf16x8 bv = *(const bf16x8*)&sXt[w * 16 + fr][k0 + fk];
#pragma unroll
      for (int mi = 0; mi < 4; ++mi) {
        bf16x8 av = *(const bf16x8*)&sM[mi * 16 + fr][k0 + fk];
        acc2[mi] = __builtin_amdgcn_mfma_f32_16x16x32_bf16(av, bv, acc2[mi], 0, 0, 0);
      }
    }
  }

  // stores
  bf16_t* yout = y2 + (size_t)dir * NROWS * D_INNER;
  bf16_t* tco = Tc_buf + (size_t)bid * 4096;
#pragma unroll
  for (int mi = 0; mi < 4; ++mi) {
#pragma unroll
    for (int r = 0; r < 4; ++r) {
      int rowl = mi * 16 + (lane >> 4) * 4 + r;
      int coll = w * 16 + fr;
      yout[ROWOF(rowl) * D_INNER + h * 64 + coll] = (bf16_t)acc2[mi][r];
      tco[rowl * 64 + coll] = (bf16_t)acc3[mi][r];
    }
  }
#undef ROWOF
}

// ---------------- K2a: parallel state prefix, in-place Tc -> S ----------------
// grid = 512: g = bid>>1 (dir*128+b*16+h), part = bid&1. 256 thr x 8 elems.
__global__ __launch_bounds__(256) void state_prefix_kernel(
    const float* __restrict__ la_buf, bf16_t* __restrict__ Tc_buf) {
  const int g = blockIdx.x >> 1;
  const int e0 = (blockIdx.x & 1) * 2048 + threadIdx.x * 8;
  bf16_t* tc = Tc_buf + (size_t)g * 32 * 4096 + e0;
  const float* la63 = la_buf + (size_t)g * 32 * 64 + 63;
  float S[8] = {};
  for (int cc = 0; cc < 32; ++cc) {
    bf16x8 t = *(const bf16x8*)(tc + (size_t)cc * 4096);
    float d = __expf(la63[cc * 64]);
    bf16_t sb[8];
#pragma unroll
    for (int j = 0; j < 8; ++j) sb[j] = (bf16_t)S[j];
    *(bf16x8*)(tc + (size_t)cc * 4096) = *(bf16x8*)sb;
    const bf16_t* tp = (const bf16_t*)&t;
#pragma unroll
    for (int j = 0; j < 8; ++j) S[j] = d * S[j] + (float)tp[j];
  }
}

// ---------------- K2b v2: Y_state apply (2048 blocks, vectorized) ----------------
__global__ __launch_bounds__(256) void ystate_kernel(
    const float* __restrict__ xbc, const bf16_t* __restrict__ S_buf,
    const float* __restrict__ la_buf, bf16_t* __restrict__ y2) {
  const int bid = blockIdx.x;
  const int hg = bid & 3, c = (bid >> 2) & 31, b = (bid >> 7) & 7, dir = bid >> 10;
  const int tid = threadIdx.x, w = tid >> 6, lane = tid & 63;
  const int fr = lane & 15, fk = (lane >> 4) * 8;
  const size_t base = (size_t)b * L_SEQ;

  __shared__ __align__(16) bf16_t sC[64][72];   // C rows, bf16, padded
  __shared__ __align__(16) float  sYf[64][72];  // f32 bounce for vectorized RMW
  __shared__ float sEla[64];

  // ---- stage C tile once (f32 -> bf16), coalesced float4 loads ----
#pragma unroll
  for (int uu = 0; uu < 4; ++uu) {
    int u = tid + uu * 256;          // 0..1023
    int row = u >> 4, q = u & 15;    // 64 rows x 16 float4
    int t = c * 64 + row;
    int tr = dir ? (L_SEQ - 1 - t) : t;
    float4 cv = *(const float4*)(xbc + (base + tr) * CONV_DIM + D_INNER + D_STATE + q * 4);
    bf16x4 cb;
    cb[0] = (bf16_t)cv.x; cb[1] = (bf16_t)cv.y; cb[2] = (bf16_t)cv.z; cb[3] = (bf16_t)cv.w;
    *(bf16x4*)&sC[row][q * 4] = cb;
  }
  __syncthreads();

  bf16_t* yout = y2 + (size_t)dir * NROWS * D_INNER;

#pragma unroll 1
  for (int hi = 0; hi < 4; ++hi) {
    const int h = hg * 4 + hi;
    const int bidh = dir * 4096 + b * 512 + h * 32 + c;   // original (c,h,b,dir) block id
    if (tid < 64) sEla[tid] = __expf(la_buf[(size_t)bidh * 64 + tid]);

    const bf16_t* Sp = S_buf + (size_t)bidh * 4096;
    f32x4 acc[4] = {};
#pragma unroll
    for (int k0 = 0; k0 < 64; k0 += 32) {
      bf16x8 bv = *(const bf16x8*)(Sp + (w * 16 + fr) * 64 + k0 + fk);
#pragma unroll
      for (int mi = 0; mi < 4; ++mi) {
        bf16x8 av = *(const bf16x8*)&sC[mi * 16 + fr][k0 + fk];
        acc[mi] = __builtin_amdgcn_mfma_f32_16x16x32_bf16(av, bv, acc[mi], 0, 0, 0);
      }
    }
    __syncthreads();   // sEla ready; previous head's sYf fully consumed

    // scale by exp(la) and drop into f32 bounce buffer
#pragma unroll
    for (int mi = 0; mi < 4; ++mi) {
#pragma unroll
      for (int r = 0; r < 4; ++r) {
        int tl = mi * 16 + (lane >> 4) * 4 + r;
        sYf[tl][w * 16 + fr] = acc[mi][r] * sEla[tl];
      }
    }
    __syncthreads();

    // vectorized RMW: 512 units of 8 consecutive bf16; 2 per thread
#pragma unroll
    for (int uu = 0; uu < 2; ++uu) {
      int u = tid + uu * 256;
      int row = u >> 3, oct = u & 7;
      int t = c * 64 + row;
      int tr = dir ? (L_SEQ - 1 - t) : t;
      bf16_t* gp = yout + (base + tr) * D_INNER + h * 64 + oct * 8;
      bf16x8 old = *(const bf16x8*)gp;
      const float* yp = &sYf[row][oct * 8];
      bf16x8 nw;
#pragma unroll
      for (int j = 0; j < 8; ++j) nw[j] = (bf16_t)((float)old[j] + yp[j]);
      *(bf16x8*)gp = nw;
    }
  }
}

// ---------------- combine: y = rmsnorm((yf+yb+D*xs) * silu(z)) * norm_w -> bf16 ----------------
__global__ __launch_bounds__(256) void combine_kernel(
    const bf16_t* __restrict__ y2, const float* __restrict__ xbc_conv,
    const float* __restrict__ z, const float* __restrict__ Dp,
    const float* __restrict__ norm_w, bf16_t* __restrict__ yn) {
  __shared__ float red[4];
  int row = blockIdx.x;
  const bf16_t* yf = y2 + (size_t)row * D_INNER;
  const bf16_t* yb = y2 + (size_t)NROWS * D_INNER + (size_t)row * D_INNER;
  const float* xs = xbc_conv + (size_t)row * CONV_DIM;
  const float* zr = z + (size_t)row * D_INNER;

  float g[4];
  float ss = 0.f;
#pragma unroll
  for (int k = 0; k < 4; ++k) {
    int c = threadIdx.x + k * 256;
    float v = (float)yf[c] + (float)yb[c] + Dp[c >> 6] * xs[c];
    float gg = v * silu_f(zr[c]);
    g[k] = gg;
    ss += gg * gg;
  }
  ss = block_sum256(ss, red);
  float r = rsqrtf(ss * (1.f / 1024.f) + EPS);
  bf16_t* yr = yn + (size_t)row * D_INNER;
#pragma unroll
  for (int k = 0; k < 4; ++k) {
    int c = threadIdx.x + k * 256;
    yr[c] = (bf16_t)(g[k] * r * norm_w[c]);
  }
}

// ---------------- launcher ----------------
extern "C" void kernel_launch(void* const* d_in, const int* in_sizes, int n_in,
                              void* d_out, int out_size, void* d_ws, size_t ws_size,
                              hipStream_t stream) {
  const float* x       = (const float*)d_in[0];
  const float* mask    = (const float*)d_in[1];
  const float* W_in    = (const float*)d_in[2];
  const float* conv_w  = (const float*)d_in[3];
  const float* conv_b  = (const float*)d_in[4];
  const float* dt_bias = (const float*)d_in[5];
  const float* A_log   = (const float*)d_in[6];
  const float* Dp      = (const float*)d_in[7];
  const float* norm_w  = (const float*)d_in[8];
  const float* W_out   = (const float*)d_in[9];
  const float* W1      = (const float*)d_in[10];
  const float* b1      = (const float*)d_in[11];
  const float* W2      = (const float*)d_in[12];
  const float* b2      = (const float*)d_in[13];

  float* out_x  = (float*)d_out;                       // 16384*512
  float* out_m  = out_x + (size_t)NROWS * 512;         // 16384*512
  float* out_dt = out_m + (size_t)NROWS * 512;         // 16384*16
  float* out_z  = out_dt + (size_t)NROWS * NHEADS;     // 16384*1024

  char* ws = (char*)d_ws;
  bf16_t* wt_in    = (bf16_t*)(ws + OFF_WT_IN);
  bf16_t* wt_out   = (bf16_t*)(ws + OFF_WT_OUT);
  bf16_t* w1t      = (bf16_t*)(ws + OFF_W1T);
  bf16_t* w2t      = (bf16_t*)(ws + OFF_W2T);
  bf16_t* u_bf     = (bf16_t*)(ws + OFF_U);            // reused: la_buf (scan), h_bf (ffn)
  float*  xbc_raw  = (float*)(ws + OFF_XBC_RAW);       // reused: Tc/S_buf (scan), gelu bf16 (ffn)
  float*  xbc_conv = (float*)(ws + OFF_XBC_CONV);
  bf16_t* y2       = (bf16_t*)(ws + OFF_Y2);
  bf16_t* yn       = (bf16_t*)(ws + OFF_YN);
  bf16_t* h_bf     = u_bf;
  bf16_t* gelu_bf  = (bf16_t*)(ws + OFF_XBC_RAW);
  bf16_t* Tc_buf   = (bf16_t*)(ws + OFF_XBC_RAW);      // 8192*4096 bf16 = 67 MB <= 75 MB region
  float*  la_buf   = (float*)(ws + OFF_U);             // 8192*64 f32 = 2 MB <= 16.7 MB region

  // 1. weights -> bf16 transposed
  prep_weights_kernel<<<14624, 256, 0, stream>>>(W_in, W_out, W1, W2, wt_in, wt_out, w1t, w2t);
  // 2. u = rmsnorm(x*mask)
  rmsnorm_in_kernel<<<NROWS, 256, 0, stream>>>(x, mask, u_bf);
  // 3. zxbcdt = u @ W_in, split into z / xBC / dt(softplus)
  gemm_kernel<1><<<dim3(18, 128), 256, 0, stream>>>(u_bf, wt_in, NROWS, D_IN_PROJ, 512,
                                                    out_z, xbc_raw, out_dt, nullptr, dt_bias, nullptr);
  // 4. conv1d + silu + mask
  conv_silu_kernel<<<NROWS, 384, 0, stream>>>(xbc_raw, conv_w, conv_b, mask, xbc_conv);
  // 5a. SSD chunked scan: per-chunk GEMMs (Y_intra, Tc, la)
  scan_chunk_kernel<<<8192, 256, 0, stream>>>(xbc_conv, out_dt, A_log, y2, Tc_buf, la_buf);
  // 5b. parallel state prefix (in-place Tc -> S)
  state_prefix_kernel<<<512, 256, 0, stream>>>(la_buf, Tc_buf);
  // 5c. Y_state apply (vectorized MFMA + LDS-bounced 16B RMW)
  ystate_kernel<<<2048, 256, 0, stream>>>(xbc_conv, Tc_buf, la_buf, y2);
  // 6. combine + gated rmsnorm
  combine_kernel<<<NROWS, 256, 0, stream>>>(y2, xbc_conv, out_z, Dp, norm_w, yn);
  // 7. m = yn @ W_out
  gemm_kernel<0><<<dim3(4, 128), 256, 0, stream>>>(yn, wt_out, NROWS, 512, 1024,
                                                   out_m, nullptr, nullptr, nullptr, nullptr, nullptr);
  // 8. h = rmsnorm(2m)
  rmsnorm2_kernel<<<NROWS, 256, 0, stream>>>(out_m, h_bf);
  // 9. g = gelu(h @ W1 + b1)
  gemm_kernel<2><<<dim3(16, 128), 256, 0, stream>>>(h_bf, w1t, NROWS, D_FF, 512,
                                                    nullptr, nullptr, nullptr, gelu_bf, b1, nullptr);
  // 10. x = 2m + g @ W2 + b2
  gemm_kernel<3><<<dim3(4, 128), 256, 0, stream>>>(gelu_bf, w2t, NROWS, 512, D_FF,
                                                   out_x, nullptr, nullptr, nullptr, b2, out_m);
}

// Round 5
// 663.394 us; speedup vs baseline: 1.0271x; 1.0271x over previous
//
#include <hip/hip_runtime.h>
#include <cstdint>
#include <cstddef>

// ---------------- constants ----------------
#define L_SEQ   2048
#define NROWS   16384            // B*L = 8*2048
#define D_MODEL 512
#define D_INNER 1024
#define D_STATE 64
#define NHEADS  16
#define CONV_DIM 1152
#define D_IN_PROJ 2192
#define D_FF 2048
#define EPS 1e-6f

typedef __bf16 bf16_t;
typedef __bf16 bf16x8 __attribute__((ext_vector_type(8)));
typedef __bf16 bf16x4 __attribute__((ext_vector_type(4)));
typedef float  f32x4  __attribute__((ext_vector_type(4)));

// workspace layout (bytes)
#define OFF_WT_IN    0ull                       // 2192*512 bf16  = 2,244,608
#define OFF_WT_OUT   2244608ull                 // 512*1024 bf16  = 1,048,576
#define OFF_W1T      3293184ull                 // 2048*512 bf16  = 2,097,152
#define OFF_W2T      5390336ull                 // 512*2048 bf16  = 2,097,152
#define OFF_U        7487488ull                 // 16384*512 bf16 (u_bf; reused: la_buf during scan, h_bf later)
#define OFF_XBC_RAW  24264704ull                // 16384*1152 f32 (xbc_raw; reused: Tc/S_buf during scan, gelu bf16 later)
#define OFF_XBC_CONV 99762176ull                // 16384*1152 bf16 now (37.75 MB used of 75.5 MB region)
#define OFF_Y2       175259648ull               // 2*16384*1024 bf16 = 67,108,864
#define OFF_YN       242368512ull               // 16384*1024 bf16 = 33,554,432
// total ~276 MB

// ---------------- helpers ----------------
__device__ __forceinline__ void gl_lds16(const void* g, void* s) {
  __builtin_amdgcn_global_load_lds(
      (__attribute__((address_space(1))) void*)(void*)g,
      (__attribute__((address_space(3))) void*)s, 16, 0, 0);
}

__device__ __forceinline__ float block_sum256(float v, float* red) {
#pragma unroll
  for (int o = 32; o > 0; o >>= 1) v += __shfl_xor(v, o, 64);
  int w = threadIdx.x >> 6;
  if ((threadIdx.x & 63) == 0) red[w] = v;
  __syncthreads();
  return red[0] + red[1] + red[2] + red[3];
}

__device__ __forceinline__ float softplus_f(float x) {
  return (x > 20.f) ? x : log1pf(expf(x));
}
__device__ __forceinline__ float silu_f(float x) {
  return x / (1.f + expf(-x));
}
__device__ __forceinline__ float gelu_tanh_f(float x) {
  float x3 = x * x * x;
  return 0.5f * x * (1.f + tanhf(0.7978845608f * (x + 0.044715f * x3)));
}

// ---------------- weight prep: fp32 -> bf16, transposed ----------------
__global__ __launch_bounds__(256) void prep_weights_kernel(
    const float* __restrict__ W_in, const float* __restrict__ W_out,
    const float* __restrict__ W1, const float* __restrict__ W2,
    bf16_t* __restrict__ wt_in, bf16_t* __restrict__ wt_out,
    bf16_t* __restrict__ w1t, bf16_t* __restrict__ w2t) {
  const int S1 = D_IN_PROJ * 512;   // 1122304
  const int S2 = 512 * 1024;        // 524288
  const int S3 = 2048 * 512;        // 1048576
  const int S4 = 512 * 2048;        // 1048576
  const int total = S1 + S2 + S3 + S4;
  for (int i = blockIdx.x * 256 + threadIdx.x; i < total; i += gridDim.x * 256) {
    if (i < S1) {
      int n = i / 512, k = i - n * 512;
      wt_in[i] = (bf16_t)W_in[k * D_IN_PROJ + n];
    } else if (i < S1 + S2) {
      int j = i - S1; int n = j >> 10, k = j & 1023;
      wt_out[j] = (bf16_t)W_out[k * 512 + n];
    } else if (i < S1 + S2 + S3) {
      int j = i - S1 - S2; int n = j >> 9, k = j & 511;
      w1t[j] = (bf16_t)W1[k * 2048 + n];
    } else {
      int j = i - S1 - S2 - S3; int n = j >> 11, k = j & 2047;
      w2t[j] = (bf16_t)W2[k * 512 + n];
    }
  }
}

// ---------------- rmsnorm of masked input -> bf16 ----------------
__global__ __launch_bounds__(256) void rmsnorm_in_kernel(
    const float* __restrict__ x, const float* __restrict__ mask,
    bf16_t* __restrict__ u) {
  __shared__ float red[4];
  int row = blockIdx.x;
  float mk = mask[row];
  const float* xr = x + (size_t)row * 512;
  float v0 = xr[threadIdx.x] * mk;
  float v1 = xr[threadIdx.x + 256] * mk;
  float ss = block_sum256(v0 * v0 + v1 * v1, red);
  float r = rsqrtf(ss * (1.f / 512.f) + EPS);
  bf16_t* ur = u + (size_t)row * 512;
  ur[threadIdx.x] = (bf16_t)(v0 * r);
  ur[threadIdx.x + 256] = (bf16_t)(v1 * r);
}

// ---------------- rmsnorm of 2*m -> bf16 ----------------
__global__ __launch_bounds__(256) void rmsnorm2_kernel(
    const float* __restrict__ m, bf16_t* __restrict__ h) {
  __shared__ float red[4];
  int row = blockIdx.x;
  const float* mr = m + (size_t)row * 512;
  float v0 = 2.f * mr[threadIdx.x];
  float v1 = 2.f * mr[threadIdx.x + 256];
  float ss = block_sum256(v0 * v0 + v1 * v1, red);
  float r = rsqrtf(ss * (1.f / 512.f) + EPS);
  bf16_t* hr = h + (size_t)row * 512;
  hr[threadIdx.x] = (bf16_t)(v0 * r);
  hr[threadIdx.x + 256] = (bf16_t)(v1 * r);
}

// ---------------- MFMA GEMM: C[M,N] = A[M,K](bf16) @ Bt[N,K](bf16)^T ----------------
// v4 (unchanged from R4): 2-phase double buffer, streaming-bound at ~2.5 TB/s.
template <int EPI>
__global__ __launch_bounds__(256, 2) void gemm_kernel(
    const bf16_t* __restrict__ A, const bf16_t* __restrict__ Bt,
    int M, int N, int K,
    float* __restrict__ o0, float* __restrict__ o1, float* __restrict__ o2,
    bf16_t* __restrict__ ob, const float* __restrict__ bias,
    const float* __restrict__ extra) {
  __shared__ bf16_t As[2][128 * 32];
  __shared__ bf16_t Bs[2][128 * 32];
  const int tid = threadIdx.x;
  const int lane = tid & 63;
  const int w = tid >> 6;
  const int tileM = blockIdx.y * 128;
  const int tileN = blockIdx.x * 128;

  f32x4 acc[4][4] = {};

  const int wm = (w >> 1) * 64;
  const int wn = (w & 1) * 64;
  const int fr = lane & 15;
  const int fk = (lane >> 4) * 8;

  const int rsub = lane >> 2;                  // row-within-16 of this lane's 16B chunk
  const int cb   = (lane & 3) * 16;            // byte col within 64B row

  auto stage = [&](int buf, int k0) {
#pragma unroll
    for (int i = 0; i < 2; ++i) {
      int rloc = w * 32 + i * 16 + rsub;
      const char* ga = (const char*)(A + (size_t)(tileM + rloc) * K + k0) + cb;
      gl_lds16(ga, (void*)&As[buf][(w * 32 + i * 16) * 32]);
      int rn = tileN + rloc;
      if (rn >= N) rn = N - 1;
      const char* gb = (const char*)(Bt + (size_t)rn * K + k0) + cb;
      gl_lds16(gb, (void*)&Bs[buf][(w * 32 + i * 16) * 32]);
    }
  };

  const int nt = K >> 5;
  stage(0, 0);
  __syncthreads();
  int cur = 0;
  for (int t = 0; t < nt; ++t) {
    if (t + 1 < nt) stage(cur ^ 1, (t + 1) << 5);

    bf16x8 av[4], bv[4];
#pragma unroll
    for (int i = 0; i < 4; ++i)
      av[i] = *(const bf16x8*)&As[cur][(wm + i * 16 + fr) * 32 + fk];
#pragma unroll
    for (int j = 0; j < 4; ++j)
      bv[j] = *(const bf16x8*)&Bs[cur][(wn + j * 16 + fr) * 32 + fk];
#pragma unroll
    for (int i = 0; i < 4; ++i)
#pragma unroll
      for (int j = 0; j < 4; ++j)
        acc[i][j] = __builtin_amdgcn_mfma_f32_16x16x32_bf16(av[i], bv[j], acc[i][j], 0, 0, 0);

    __syncthreads();
    cur ^= 1;
  }

  // -------- epilogue (R1-proven scalar form) --------
  const int cn = lane & 15;
  const int r0 = (lane >> 4) * 4;
#pragma unroll
  for (int i = 0; i < 4; ++i) {
#pragma unroll
    for (int j = 0; j < 4; ++j) {
      int gn = tileN + wn + j * 16 + cn;
      if (gn >= N) continue;
#pragma unroll
      for (int r = 0; r < 4; ++r) {
        int gm = tileM + wm + i * 16 + r0 + r;
        float v = acc[i][j][r];
        if (EPI == 0) {
          o0[(size_t)gm * N + gn] = v;
        } else if (EPI == 1) {
          if (gn < D_INNER) {
            o0[(size_t)gm * D_INNER + gn] = v;                       // z
          } else if (gn < D_INNER + CONV_DIM) {
            o1[(size_t)gm * CONV_DIM + (gn - D_INNER)] = v;          // xBC raw
          } else {
            int hh = gn - (D_INNER + CONV_DIM);
            o2[(size_t)gm * NHEADS + hh] = softplus_f(v + bias[hh]); // dt
          }
        } else if (EPI == 2) {
          ob[(size_t)gm * N + gn] = (bf16_t)gelu_tanh_f(v + bias[gn]);
        } else if (EPI == 3) {
          o0[(size_t)gm * N + gn] = v + bias[gn] + 2.f * extra[(size_t)gm * N + gn];
        }
      }
    }
  }
}

// ---------------- causal conv1d (k=4) + silu + mask -> bf16 ----------------
// v2: 4-col vector units (float4 loads, bf16x4 store). 320 thr, 288 active.
__global__ __launch_bounds__(320) void conv_silu_kernel(
    const float* __restrict__ xbc_raw, const float* __restrict__ conv_w,
    const float* __restrict__ conv_b, const float* __restrict__ mask,
    bf16_t* __restrict__ xbc_conv) {
  int row = blockIdx.x;
  int tid = threadIdx.x;
  if (tid >= 288) return;
  int t = row & (L_SEQ - 1);
  float mk = mask[row];
  int c = tid * 4;
  const float* base = xbc_raw + (size_t)row * CONV_DIM + c;
  float4 z4 = {0.f, 0.f, 0.f, 0.f};
  float4 r0 = *(const float4*)base;
  float4 r1 = (t >= 1) ? *(const float4*)(base - CONV_DIM) : z4;
  float4 r2 = (t >= 2) ? *(const float4*)(base - 2 * CONV_DIM) : z4;
  float4 r3 = (t >= 3) ? *(const float4*)(base - 3 * CONV_DIM) : z4;
  const float* p0 = (const float*)&r0;
  const float* p1 = (const float*)&r1;
  const float* p2 = (const float*)&r2;
  const float* p3 = (const float*)&r3;
  bf16x4 o;
#pragma unroll
  for (int j = 0; j < 4; ++j) {
    float4 wv = ((const float4*)conv_w)[c + j];   // conv_w[c+j][0..3]
    float acc = conv_b[c + j] + wv.x * p3[j] + wv.y * p2[j] + wv.z * p1[j] + wv.w * p0[j];
    o[j] = (bf16_t)(silu_f(acc) * mk);
  }
  *(bf16x4*)&xbc_conv[(size_t)row * CONV_DIM + c] = o;
}

// ================= SSD chunked scan =================
// xbc is now bf16 (rounding moved pre-store; MFMA inputs identical bits).

// ---------------- K1: per-chunk parallel kernel (8192 blocks) ----------------
__global__ __launch_bounds__(256) void scan_chunk_kernel(
    const bf16_t* __restrict__ xbc, const float* __restrict__ dt_all,
    const float* __restrict__ A_log,
    bf16_t* __restrict__ y2, bf16_t* __restrict__ Tc_buf,
    float* __restrict__ la_buf) {
  const int bid = blockIdx.x;
  const int c = bid & 31, h = (bid >> 5) & 15, b = (bid >> 9) & 7, dir = bid >> 12;
  const float A_h = -expf(A_log[h]);
  const int tid = threadIdx.x, w = tid >> 6, lane = tid & 63;
  const int fr = lane & 15, fk = (lane >> 4) * 8;

  __shared__ __align__(16) bf16_t sB[64][72];    // B rows [s][n]; aliased as M[t][s] later
  __shared__ __align__(16) bf16_t sC[64][72];    // C rows [t][n]
  __shared__ __align__(16) bf16_t sXt[64][72];   // X^T [p][s]
  __shared__ __align__(16) bf16_t sBwt[64][72];  // (w.B)^T [n][s]
  __shared__ float sLa[64], sDt[64], sW[64];

  const size_t base = (size_t)b * L_SEQ;
#define ROWOF(i) (base + (size_t)(dir ? (L_SEQ - 1 - (c * 64 + (i))) : (c * 64 + (i))))

  if (tid < 64) sDt[tid] = dt_all[ROWOF(tid) * NHEADS + h];

  float bB[16];
#pragma unroll
  for (int r = 0; r < 16; ++r) {
    int i = w * 16 + r;
    const bf16_t* src = xbc + ROWOF(i) * CONV_DIM;
    bf16_t xv = src[h * 64 + lane];
    bf16_t bv = src[D_INNER + lane];
    bf16_t cv = src[D_INNER + D_STATE + lane];
    bB[r] = (float)bv;
    sB[i][lane] = bv;
    sC[i][lane] = cv;
    sXt[lane][i] = xv;
  }
  __syncthreads();

  if (w == 0) {
    float v = sDt[lane] * A_h;
#pragma unroll
    for (int d = 1; d < 64; d <<= 1) {
      float o = __shfl_up(v, d, 64);
      if (lane >= d) v += o;
    }
    sLa[lane] = v;
    float la63 = __shfl(v, 63, 64);
    sW[lane] = __expf(la63 - v) * sDt[lane];
  }
  __syncthreads();

  // weighted-transposed B, and la out
#pragma unroll
  for (int r = 0; r < 16; ++r) {
    int i = w * 16 + r;
    sBwt[lane][i] = (bf16_t)(bB[r] * sW[i]);
  }
  if (tid < 64) la_buf[(size_t)bid * 64 + tid] = sLa[tid];

  // GEMM1: Gt[s, t-tile w] = B @ C^T (skip all-zero upper s-tiles: mi > w)
  f32x4 acc1[4] = {};
#pragma unroll
  for (int k0 = 0; k0 < 64; k0 += 32) {
    bf16x8 bv = *(const bf16x8*)&sC[w * 16 + fr][k0 + fk];
#pragma unroll
    for (int mi = 0; mi < 4; ++mi) {
      if (mi <= w) {
        bf16x8 av = *(const bf16x8*)&sB[mi * 16 + fr][k0 + fk];
        acc1[mi] = __builtin_amdgcn_mfma_f32_16x16x32_bf16(av, bv, acc1[mi], 0, 0, 0);
      }
    }
  }
  __syncthreads();   // GEMM1 reads done (sB can be overwritten); sBwt visible

  // build M[t][s] into sB alias
  {
    bf16_t (*sM)[72] = sB;
    float la_t = sLa[w * 16 + fr];
    int t = w * 16 + fr;
#pragma unroll
    for (int mi = 0; mi < 4; ++mi) {
#pragma unroll
      for (int r = 0; r < 4; ++r) {
        int s = mi * 16 + (lane >> 4) * 4 + r;
        float mv = 0.f;
        if (s <= t) mv = acc1[mi][r] * __expf(la_t - sLa[s]) * sDt[s];
        sM[t][s] = (bf16_t)mv;
      }
    }
  }

  // GEMM3: Tc[p, n-tile w] = X^T @ Bw  (independent of M writes)
  f32x4 acc3[4] = {};
#pragma unroll
  for (int k0 = 0; k0 < 64; k0 += 32) {
    bf16x8 bv = *(const bf16x8*)&sBwt[w * 16 + fr][k0 + fk];
#pragma unroll
    for (int mi = 0; mi < 4; ++mi) {
      bf16x8 av = *(const bf16x8*)&sXt[mi * 16 + fr][k0 + fk];
      acc3[mi] = __builtin_amdgcn_mfma_f32_16x16x32_bf16(av, bv, acc3[mi], 0, 0, 0);
    }
  }
  __syncthreads();   // M visible

  // GEMM2: Y[t, p-tile w] = M @ X
  f32x4 acc2[4] = {};
  {
    bf16_t (*sM)[72] = sB;
#pragma unroll
    for (int k0 = 0; k0 < 64; k0 += 32) {
      bf16x8 bv = *(const bf16x8*)&sXt[w * 16 + fr][k0 + fk];
#pragma unroll
      for (int mi = 0; mi < 4; ++mi) {
        bf16x8 av = *(const bf16x8*)&sM[mi * 16 + fr][k0 + fk];
        acc2[mi] = __builtin_amdgcn_mfma_f32_16x16x32_bf16(av, bv, acc2[mi], 0, 0, 0);
      }
    }
  }

  // stores
  bf16_t* yout = y2 + (size_t)dir * NROWS * D_INNER;
  bf16_t* tco = Tc_buf + (size_t)bid * 4096;
#pragma unroll
  for (int mi = 0; mi < 4; ++mi) {
#pragma unroll
    for (int r = 0; r < 4; ++r) {
      int rowl = mi * 16 + (lane >> 4) * 4 + r;
      int coll = w * 16 + fr;
      yout[ROWOF(rowl) * D_INNER + h * 64 + coll] = (bf16_t)acc2[mi][r];
      tco[rowl * 64 + coll] = (bf16_t)acc3[mi][r];
    }
  }
#undef ROWOF
}

// ---------------- K2a: parallel state prefix, in-place Tc -> S ----------------
// grid = 512: g = bid>>1 (dir*128+b*16+h), part = bid&1. 256 thr x 8 elems.
__global__ __launch_bounds__(256) void state_prefix_kernel(
    const float* __restrict__ la_buf, bf16_t* __restrict__ Tc_buf) {
  const int g = blockIdx.x >> 1;
  const int e0 = (blockIdx.x & 1) * 2048 + threadIdx.x * 8;
  bf16_t* tc = Tc_buf + (size_t)g * 32 * 4096 + e0;
  const float* la63 = la_buf + (size_t)g * 32 * 64 + 63;
  float S[8] = {};
  for (int cc = 0; cc < 32; ++cc) {
    bf16x8 t = *(const bf16x8*)(tc + (size_t)cc * 4096);
    float d = __expf(la63[cc * 64]);
    bf16_t sb[8];
#pragma unroll
    for (int j = 0; j < 8; ++j) sb[j] = (bf16_t)S[j];
    *(bf16x8*)(tc + (size_t)cc * 4096) = *(bf16x8*)sb;
    const bf16_t* tp = (const bf16_t*)&t;
#pragma unroll
    for (int j = 0; j < 8; ++j) S[j] = d * S[j] + (float)tp[j];
  }
}

// ---------------- K2b: Y_state apply (2048 blocks, vectorized, bf16 xbc) ----------------
__global__ __launch_bounds__(256) void ystate_kernel(
    const bf16_t* __restrict__ xbc, const bf16_t* __restrict__ S_buf,
    const float* __restrict__ la_buf, bf16_t* __restrict__ y2) {
  const int bid = blockIdx.x;
  const int hg = bid & 3, c = (bid >> 2) & 31, b = (bid >> 7) & 7, dir = bid >> 10;
  const int tid = threadIdx.x, w = tid >> 6, lane = tid & 63;
  const int fr = lane & 15, fk = (lane >> 4) * 8;
  const size_t base = (size_t)b * L_SEQ;

  __shared__ __align__(16) bf16_t sC[64][72];   // C rows, bf16, padded
  __shared__ __align__(16) float  sYf[64][72];  // f32 bounce for vectorized RMW
  __shared__ float sEla[64];

  // ---- stage C tile once: pure bf16x8 copy (512 units) ----
#pragma unroll
  for (int uu = 0; uu < 2; ++uu) {
    int u = tid + uu * 256;          // 0..511
    int row = u >> 3, q = u & 7;     // 64 rows x 8 units of 8 bf16
    int t = c * 64 + row;
    int tr = dir ? (L_SEQ - 1 - t) : t;
    bf16x8 cv = *(const bf16x8*)(xbc + (base + tr) * CONV_DIM + D_INNER + D_STATE + q * 8);
    *(bf16x8*)&sC[row][q * 8] = cv;
  }
  __syncthreads();

  bf16_t* yout = y2 + (size_t)dir * NROWS * D_INNER;

#pragma unroll 1
  for (int hi = 0; hi < 4; ++hi) {
    const int h = hg * 4 + hi;
    const int bidh = dir * 4096 + b * 512 + h * 32 + c;   // original (c,h,b,dir) block id
    if (tid < 64) sEla[tid] = __expf(la_buf[(size_t)bidh * 64 + tid]);

    const bf16_t* Sp = S_buf + (size_t)bidh * 4096;
    f32x4 acc[4] = {};
#pragma unroll
    for (int k0 = 0; k0 < 64; k0 += 32) {
      bf16x8 bv = *(const bf16x8*)(Sp + (w * 16 + fr) * 64 + k0 + fk);
#pragma unroll
      for (int mi = 0; mi < 4; ++mi) {
        bf16x8 av = *(const bf16x8*)&sC[mi * 16 + fr][k0 + fk];
        acc[mi] = __builtin_amdgcn_mfma_f32_16x16x32_bf16(av, bv, acc[mi], 0, 0, 0);
      }
    }
    __syncthreads();   // sEla ready; previous head's sYf fully consumed

    // scale by exp(la) and drop into f32 bounce buffer
#pragma unroll
    for (int mi = 0; mi < 4; ++mi) {
#pragma unroll
      for (int r = 0; r < 4; ++r) {
        int tl = mi * 16 + (lane >> 4) * 4 + r;
        sYf[tl][w * 16 + fr] = acc[mi][r] * sEla[tl];
      }
    }
    __syncthreads();

    // vectorized RMW: 512 units of 8 consecutive bf16; 2 per thread
#pragma unroll
    for (int uu = 0; uu < 2; ++uu) {
      int u = tid + uu * 256;
      int row = u >> 3, oct = u & 7;
      int t = c * 64 + row;
      int tr = dir ? (L_SEQ - 1 - t) : t;
      bf16_t* gp = yout + (base + tr) * D_INNER + h * 64 + oct * 8;
      bf16x8 old = *(const bf16x8*)gp;
      const float* yp = &sYf[row][oct * 8];
      bf16x8 nw;
#pragma unroll
      for (int j = 0; j < 8; ++j) nw[j] = (bf16_t)((float)old[j] + yp[j]);
      *(bf16x8*)gp = nw;
    }
  }
}

// ---------------- combine: y = rmsnorm((yf+yb+D*xs) * silu(z)) * norm_w -> bf16 ----------------
// v2: 4-col-per-thread vectorized (bf16x4 / f32x4 loads).
__global__ __launch_bounds__(256) void combine_kernel(
    const bf16_t* __restrict__ y2, const bf16_t* __restrict__ xbc_conv,
    const float* __restrict__ z, const float* __restrict__ Dp,
    const float* __restrict__ norm_w, bf16_t* __restrict__ yn) {
  __shared__ float red[4];
  int row = blockIdx.x;
  int c0 = threadIdx.x * 4;
  const bf16_t* yf = y2 + (size_t)row * D_INNER;
  const bf16_t* yb = y2 + (size_t)NROWS * D_INNER + (size_t)row * D_INNER;
  const bf16_t* xs = xbc_conv + (size_t)row * CONV_DIM;
  const float* zr = z + (size_t)row * D_INNER;

  bf16x4 vf = *(const bf16x4*)&yf[c0];
  bf16x4 vb = *(const bf16x4*)&yb[c0];
  bf16x4 vx = *(const bf16x4*)&xs[c0];
  f32x4 vz = *(const f32x4*)&zr[c0];
  float Dh = Dp[c0 >> 6];

  float g[4];
  float ss = 0.f;
#pragma unroll
  for (int j = 0; j < 4; ++j) {
    float v = (float)vf[j] + (float)vb[j] + Dh * (float)vx[j];
    float gg = v * silu_f(vz[j]);
    g[j] = gg;
    ss += gg * gg;
  }
  ss = block_sum256(ss, red);
  float r = rsqrtf(ss * (1.f / 1024.f) + EPS);
  bf16x4 o;
#pragma unroll
  for (int j = 0; j < 4; ++j) o[j] = (bf16_t)(g[j] * r * norm_w[c0 + j]);
  *(bf16x4*)&yn[(size_t)row * D_INNER + c0] = o;
}

// ---------------- launcher ----------------
extern "C" void kernel_launch(void* const* d_in, const int* in_sizes, int n_in,
                              void* d_out, int out_size, void* d_ws, size_t ws_size,
                              hipStream_t stream) {
  const float* x       = (const float*)d_in[0];
  const float* mask    = (const float*)d_in[1];
  const float* W_in    = (const float*)d_in[2];
  const float* conv_w  = (const float*)d_in[3];
  const float* conv_b  = (const float*)d_in[4];
  const float* dt_bias = (const float*)d_in[5];
  const float* A_log   = (const float*)d_in[6];
  const float* Dp      = (const float*)d_in[7];
  const float* norm_w  = (const float*)d_in[8];
  const float* W_out   = (const float*)d_in[9];
  const float* W1      = (const float*)d_in[10];
  const float* b1      = (const float*)d_in[11];
  const float* W2      = (const float*)d_in[12];
  const float* b2      = (const float*)d_in[13];

  float* out_x  = (float*)d_out;                       // 16384*512
  float* out_m  = out_x + (size_t)NROWS * 512;         // 16384*512
  float* out_dt = out_m + (size_t)NROWS * 512;         // 16384*16
  float* out_z  = out_dt + (size_t)NROWS * NHEADS;     // 16384*1024

  char* ws = (char*)d_ws;
  bf16_t* wt_in    = (bf16_t*)(ws + OFF_WT_IN);
  bf16_t* wt_out   = (bf16_t*)(ws + OFF_WT_OUT);
  bf16_t* w1t      = (bf16_t*)(ws + OFF_W1T);
  bf16_t* w2t      = (bf16_t*)(ws + OFF_W2T);
  bf16_t* u_bf     = (bf16_t*)(ws + OFF_U);            // reused: la_buf (scan), h_bf (ffn)
  float*  xbc_raw  = (float*)(ws + OFF_XBC_RAW);       // reused: Tc/S_buf (scan), gelu bf16 (ffn)
  bf16_t* xbc_conv = (bf16_t*)(ws + OFF_XBC_CONV);     // now bf16
  bf16_t* y2       = (bf16_t*)(ws + OFF_Y2);
  bf16_t* yn       = (bf16_t*)(ws + OFF_YN);
  bf16_t* h_bf     = u_bf;
  bf16_t* gelu_bf  = (bf16_t*)(ws + OFF_XBC_RAW);
  bf16_t* Tc_buf   = (bf16_t*)(ws + OFF_XBC_RAW);      // 8192*4096 bf16 = 67 MB <= 75 MB region
  float*  la_buf   = (float*)(ws + OFF_U);             // 8192*64 f32 = 2 MB <= 16.7 MB region

  // 1. weights -> bf16 transposed
  prep_weights_kernel<<<14624, 256, 0, stream>>>(W_in, W_out, W1, W2, wt_in, wt_out, w1t, w2t);
  // 2. u = rmsnorm(x*mask)
  rmsnorm_in_kernel<<<NROWS, 256, 0, stream>>>(x, mask, u_bf);
  // 3. zxbcdt = u @ W_in, split into z / xBC / dt(softplus)
  gemm_kernel<1><<<dim3(18, 128), 256, 0, stream>>>(u_bf, wt_in, NROWS, D_IN_PROJ, 512,
                                                    out_z, xbc_raw, out_dt, nullptr, dt_bias, nullptr);
  // 4. conv1d + silu + mask -> bf16
  conv_silu_kernel<<<NROWS, 320, 0, stream>>>(xbc_raw, conv_w, conv_b, mask, xbc_conv);
  // 5a. SSD chunked scan: per-chunk GEMMs (Y_intra, Tc, la)
  scan_chunk_kernel<<<8192, 256, 0, stream>>>(xbc_conv, out_dt, A_log, y2, Tc_buf, la_buf);
  // 5b. parallel state prefix (in-place Tc -> S)
  state_prefix_kernel<<<512, 256, 0, stream>>>(la_buf, Tc_buf);
  // 5c. Y_state apply (vectorized MFMA + LDS-bounced 16B RMW)
  ystate_kernel<<<2048, 256, 0, stream>>>(xbc_conv, Tc_buf, la_buf, y2);
  // 6. combine + gated rmsnorm
  combine_kernel<<<NROWS, 256, 0, stream>>>(y2, xbc_conv, out_z, Dp, norm_w, yn);
  // 7. m = yn @ W_out
  gemm_kernel<0><<<dim3(4, 128), 256, 0, stream>>>(yn, wt_out, NROWS, 512, 1024,
                                                   out_m, nullptr, nullptr, nullptr, nullptr, nullptr);
  // 8. h = rmsnorm(2m)
  rmsnorm2_kernel<<<NROWS, 256, 0, stream>>>(out_m, h_bf);
  // 9. g = gelu(h @ W1 + b1)
  gemm_kernel<2><<<dim3(16, 128), 256, 0, stream>>>(h_bf, w1t, NROWS, D_FF, 512,
                                                    nullptr, nullptr, nullptr, gelu_bf, b1, nullptr);
  // 10. x = 2m + g @ W2 + b2
  gemm_kernel<3><<<dim3(4, 128), 256, 0, stream>>>(gelu_bf, w2t, NROWS, 512, D_FF,
                                                   out_x, nullptr, nullptr, nullptr, b2, out_m);
}

// Round 6
// 624.528 us; speedup vs baseline: 1.0910x; 1.0622x over previous
//
#include <hip/hip_runtime.h>
#include <cstdint>
#include <cstddef>

// ---------------- constants ----------------
#define L_SEQ   2048
#define NROWS   16384            // B*L = 8*2048
#define D_MODEL 512
#define D_INNER 1024
#define D_STATE 64
#define NHEADS  16
#define CONV_DIM 1152
#define D_IN_PROJ 2192
#define D_FF 2048
#define EPS 1e-6f

typedef __bf16 bf16_t;
typedef __bf16 bf16x8 __attribute__((ext_vector_type(8)));
typedef __bf16 bf16x4 __attribute__((ext_vector_type(4)));
typedef float  f32x4  __attribute__((ext_vector_type(4)));

// workspace layout (bytes)
#define OFF_WT_IN    0ull                       // 2192*512 bf16  = 2,244,608
#define OFF_WT_OUT   2244608ull                 // 512*1024 bf16  = 1,048,576
#define OFF_W1T      3293184ull                 // 2048*512 bf16  = 2,097,152
#define OFF_W2T      5390336ull                 // 512*2048 bf16  = 2,097,152
#define OFF_U        7487488ull                 // 16384*512 bf16 (u_bf; reused: la_buf during scan, h_bf later)
#define OFF_XBC_RAW  24264704ull                // 16384*1152 bf16 (xbc_bf; reused: Tc/S_buf during scan, gelu bf16 later)
#define OFF_XBC_CONV 99762176ull                // 16384*1152 bf16
#define OFF_Y2       175259648ull               // 2*16384*1024 bf16 = 67,108,864
#define OFF_YN       242368512ull               // 16384*1024 bf16 = 33,554,432
// total ~276 MB

// ---------------- helpers ----------------
__device__ __forceinline__ void gl_lds16(const void* g, void* s) {
  __builtin_amdgcn_global_load_lds(
      (__attribute__((address_space(1))) void*)(void*)g,
      (__attribute__((address_space(3))) void*)s, 16, 0, 0);
}

__device__ __forceinline__ float block_sum256(float v, float* red) {
#pragma unroll
  for (int o = 32; o > 0; o >>= 1) v += __shfl_xor(v, o, 64);
  int w = threadIdx.x >> 6;
  if ((threadIdx.x & 63) == 0) red[w] = v;
  __syncthreads();
  return red[0] + red[1] + red[2] + red[3];
}

__device__ __forceinline__ float softplus_f(float x) {
  return (x > 20.f) ? x : log1pf(expf(x));
}
__device__ __forceinline__ float silu_f(float x) {
  return x / (1.f + expf(-x));
}
__device__ __forceinline__ float gelu_tanh_f(float x) {
  float x3 = x * x * x;
  return 0.5f * x * (1.f + tanhf(0.7978845608f * (x + 0.044715f * x3)));
}

// ---------------- weight prep v2: LDS 32x32 tile transpose, f32 -> bf16 ----------------
// dst[c][r] = src[r][c]; src is R x C row-major f32, dst is C x R row-major bf16.
__global__ __launch_bounds__(256) void transpose_cast_kernel(
    const float* __restrict__ src, bf16_t* __restrict__ dst, int R, int C) {
  __shared__ float tile[32][33];
  const int tx = threadIdx.x & 31;
  const int ty = threadIdx.x >> 5;          // 0..7
  const int r0 = blockIdx.y * 32;
  const int c0 = blockIdx.x * 32;
#pragma unroll
  for (int j = 0; j < 4; ++j) {
    int r = r0 + ty + j * 8;
    int c = c0 + tx;
    if (r < R && c < C) tile[ty + j * 8][tx] = src[(size_t)r * C + c];
  }
  __syncthreads();
#pragma unroll
  for (int j = 0; j < 4; ++j) {
    int c = c0 + ty + j * 8;
    int r = r0 + tx;
    if (c < C && r < R) dst[(size_t)c * R + r] = (bf16_t)tile[tx][ty + j * 8];
  }
}

// ---------------- rmsnorm of masked input -> bf16 ----------------
__global__ __launch_bounds__(256) void rmsnorm_in_kernel(
    const float* __restrict__ x, const float* __restrict__ mask,
    bf16_t* __restrict__ u) {
  __shared__ float red[4];
  int row = blockIdx.x;
  float mk = mask[row];
  const float* xr = x + (size_t)row * 512;
  float v0 = xr[threadIdx.x] * mk;
  float v1 = xr[threadIdx.x + 256] * mk;
  float ss = block_sum256(v0 * v0 + v1 * v1, red);
  float r = rsqrtf(ss * (1.f / 512.f) + EPS);
  bf16_t* ur = u + (size_t)row * 512;
  ur[threadIdx.x] = (bf16_t)(v0 * r);
  ur[threadIdx.x + 256] = (bf16_t)(v1 * r);
}

// ---------------- rmsnorm of 2*m -> bf16 ----------------
__global__ __launch_bounds__(256) void rmsnorm2_kernel(
    const float* __restrict__ m, bf16_t* __restrict__ h) {
  __shared__ float red[4];
  int row = blockIdx.x;
  const float* mr = m + (size_t)row * 512;
  float v0 = 2.f * mr[threadIdx.x];
  float v1 = 2.f * mr[threadIdx.x + 256];
  float ss = block_sum256(v0 * v0 + v1 * v1, red);
  float r = rsqrtf(ss * (1.f / 512.f) + EPS);
  bf16_t* hr = h + (size_t)row * 512;
  hr[threadIdx.x] = (bf16_t)(v0 * r);
  hr[threadIdx.x + 256] = (bf16_t)(v1 * r);
}

// ---------------- MFMA GEMM: C[M,N] = A[M,K](bf16) @ Bt[N,K](bf16)^T ----------------
// v5: 2-phase double buffer; launch_bounds (256,4) for 4 blocks/CU (VGPR+AGPR=120<=128).
//     EPI=1 writes xBC segment as bf16.
template <int EPI>
__global__ __launch_bounds__(256, 4) void gemm_kernel(
    const bf16_t* __restrict__ A, const bf16_t* __restrict__ Bt,
    int M, int N, int K,
    float* __restrict__ o0, float* __restrict__ o1, float* __restrict__ o2,
    bf16_t* __restrict__ ob, const float* __restrict__ bias,
    const float* __restrict__ extra) {
  __shared__ bf16_t As[2][128 * 32];
  __shared__ bf16_t Bs[2][128 * 32];
  const int tid = threadIdx.x;
  const int lane = tid & 63;
  const int w = tid >> 6;
  const int tileM = blockIdx.y * 128;
  const int tileN = blockIdx.x * 128;

  f32x4 acc[4][4] = {};

  const int wm = (w >> 1) * 64;
  const int wn = (w & 1) * 64;
  const int fr = lane & 15;
  const int fk = (lane >> 4) * 8;

  const int rsub = lane >> 2;                  // row-within-16 of this lane's 16B chunk
  const int cb   = (lane & 3) * 16;            // byte col within 64B row

  auto stage = [&](int buf, int k0) {
#pragma unroll
    for (int i = 0; i < 2; ++i) {
      int rloc = w * 32 + i * 16 + rsub;
      const char* ga = (const char*)(A + (size_t)(tileM + rloc) * K + k0) + cb;
      gl_lds16(ga, (void*)&As[buf][(w * 32 + i * 16) * 32]);
      int rn = tileN + rloc;
      if (rn >= N) rn = N - 1;
      const char* gb = (const char*)(Bt + (size_t)rn * K + k0) + cb;
      gl_lds16(gb, (void*)&Bs[buf][(w * 32 + i * 16) * 32]);
    }
  };

  const int nt = K >> 5;
  stage(0, 0);
  __syncthreads();
  int cur = 0;
  for (int t = 0; t < nt; ++t) {
    if (t + 1 < nt) stage(cur ^ 1, (t + 1) << 5);

    bf16x8 av[4], bv[4];
#pragma unroll
    for (int i = 0; i < 4; ++i)
      av[i] = *(const bf16x8*)&As[cur][(wm + i * 16 + fr) * 32 + fk];
#pragma unroll
    for (int j = 0; j < 4; ++j)
      bv[j] = *(const bf16x8*)&Bs[cur][(wn + j * 16 + fr) * 32 + fk];
#pragma unroll
    for (int i = 0; i < 4; ++i)
#pragma unroll
      for (int j = 0; j < 4; ++j)
        acc[i][j] = __builtin_amdgcn_mfma_f32_16x16x32_bf16(av[i], bv[j], acc[i][j], 0, 0, 0);

    __syncthreads();
    cur ^= 1;
  }

  // -------- epilogue --------
  const int cn = lane & 15;
  const int r0 = (lane >> 4) * 4;
#pragma unroll
  for (int i = 0; i < 4; ++i) {
#pragma unroll
    for (int j = 0; j < 4; ++j) {
      int gn = tileN + wn + j * 16 + cn;
      if (gn >= N) continue;
#pragma unroll
      for (int r = 0; r < 4; ++r) {
        int gm = tileM + wm + i * 16 + r0 + r;
        float v = acc[i][j][r];
        if (EPI == 0) {
          o0[(size_t)gm * N + gn] = v;
        } else if (EPI == 1) {
          if (gn < D_INNER) {
            o0[(size_t)gm * D_INNER + gn] = v;                       // z (f32 output)
          } else if (gn < D_INNER + CONV_DIM) {
            ob[(size_t)gm * CONV_DIM + (gn - D_INNER)] = (bf16_t)v;  // xBC raw -> bf16
          } else {
            int hh = gn - (D_INNER + CONV_DIM);
            o2[(size_t)gm * NHEADS + hh] = softplus_f(v + bias[hh]); // dt
          }
        } else if (EPI == 2) {
          ob[(size_t)gm * N + gn] = (bf16_t)gelu_tanh_f(v + bias[gn]);
        } else if (EPI == 3) {
          o0[(size_t)gm * N + gn] = v + bias[gn] + 2.f * extra[(size_t)gm * N + gn];
        }
      }
    }
  }
}

// ---------------- causal conv1d (k=4) + silu + mask: bf16 in -> bf16 out ----------------
__global__ __launch_bounds__(320) void conv_silu_kernel(
    const bf16_t* __restrict__ xbc_raw, const float* __restrict__ conv_w,
    const float* __restrict__ conv_b, const float* __restrict__ mask,
    bf16_t* __restrict__ xbc_conv) {
  int row = blockIdx.x;
  int tid = threadIdx.x;
  if (tid >= 288) return;
  int t = row & (L_SEQ - 1);
  float mk = mask[row];
  int c = tid * 4;
  const bf16_t* base = xbc_raw + (size_t)row * CONV_DIM + c;
  bf16x4 z4 = {};
  bf16x4 r0 = *(const bf16x4*)base;
  bf16x4 r1 = (t >= 1) ? *(const bf16x4*)(base - CONV_DIM) : z4;
  bf16x4 r2 = (t >= 2) ? *(const bf16x4*)(base - 2 * CONV_DIM) : z4;
  bf16x4 r3 = (t >= 3) ? *(const bf16x4*)(base - 3 * CONV_DIM) : z4;
  bf16x4 o;
#pragma unroll
  for (int j = 0; j < 4; ++j) {
    float4 wv = ((const float4*)conv_w)[c + j];   // conv_w[c+j][0..3]
    float acc = conv_b[c + j] + wv.x * (float)r3[j] + wv.y * (float)r2[j] +
                wv.z * (float)r1[j] + wv.w * (float)r0[j];
    o[j] = (bf16_t)(silu_f(acc) * mk);
  }
  *(bf16x4*)&xbc_conv[(size_t)row * CONV_DIM + c] = o;
}

// ================= SSD chunked scan =================

// ---------------- K1: per-chunk parallel kernel (8192 blocks) ----------------
__global__ __launch_bounds__(256) void scan_chunk_kernel(
    const bf16_t* __restrict__ xbc, const float* __restrict__ dt_all,
    const float* __restrict__ A_log,
    bf16_t* __restrict__ y2, bf16_t* __restrict__ Tc_buf,
    float* __restrict__ la_buf) {
  const int bid = blockIdx.x;
  const int c = bid & 31, h = (bid >> 5) & 15, b = (bid >> 9) & 7, dir = bid >> 12;
  const float A_h = -expf(A_log[h]);
  const int tid = threadIdx.x, w = tid >> 6, lane = tid & 63;
  const int fr = lane & 15, fk = (lane >> 4) * 8;

  __shared__ __align__(16) bf16_t sB[64][72];    // B rows [s][n]; aliased as M[t][s] later
  __shared__ __align__(16) bf16_t sC[64][72];    // C rows [t][n]
  __shared__ __align__(16) bf16_t sXt[64][72];   // X^T [p][s]
  __shared__ __align__(16) bf16_t sBwt[64][72];  // (w.B)^T [n][s]
  __shared__ float sLa[64], sDt[64], sW[64];

  const size_t base = (size_t)b * L_SEQ;
#define ROWOF(i) (base + (size_t)(dir ? (L_SEQ - 1 - (c * 64 + (i))) : (c * 64 + (i))))

  if (tid < 64) sDt[tid] = dt_all[ROWOF(tid) * NHEADS + h];

  float bB[16];
#pragma unroll
  for (int r = 0; r < 16; ++r) {
    int i = w * 16 + r;
    const bf16_t* src = xbc + ROWOF(i) * CONV_DIM;
    bf16_t xv = src[h * 64 + lane];
    bf16_t bv = src[D_INNER + lane];
    bf16_t cv = src[D_INNER + D_STATE + lane];
    bB[r] = (float)bv;
    sB[i][lane] = bv;
    sC[i][lane] = cv;
    sXt[lane][i] = xv;
  }
  __syncthreads();

  if (w == 0) {
    float v = sDt[lane] * A_h;
#pragma unroll
    for (int d = 1; d < 64; d <<= 1) {
      float o = __shfl_up(v, d, 64);
      if (lane >= d) v += o;
    }
    sLa[lane] = v;
    float la63 = __shfl(v, 63, 64);
    sW[lane] = __expf(la63 - v) * sDt[lane];
  }
  __syncthreads();

  // weighted-transposed B, and la out
#pragma unroll
  for (int r = 0; r < 16; ++r) {
    int i = w * 16 + r;
    sBwt[lane][i] = (bf16_t)(bB[r] * sW[i]);
  }
  if (tid < 64) la_buf[(size_t)bid * 64 + tid] = sLa[tid];

  // GEMM1: Gt[s, t-tile w] = B @ C^T (skip all-zero upper s-tiles: mi > w)
  f32x4 acc1[4] = {};
#pragma unroll
  for (int k0 = 0; k0 < 64; k0 += 32) {
    bf16x8 bv = *(const bf16x8*)&sC[w * 16 + fr][k0 + fk];
#pragma unroll
    for (int mi = 0; mi < 4; ++mi) {
      if (mi <= w) {
        bf16x8 av = *(const bf16x8*)&sB[mi * 16 + fr][k0 + fk];
        acc1[mi] = __builtin_amdgcn_mfma_f32_16x16x32_bf16(av, bv, acc1[mi], 0, 0, 0);
      }
    }
  }
  __syncthreads();   // GEMM1 reads done (sB can be overwritten); sBwt visible

  // build M[t][s] into sB alias
  {
    bf16_t (*sM)[72] = sB;
    float la_t = sLa[w * 16 + fr];
    int t = w * 16 + fr;
#pragma unroll
    for (int mi = 0; mi < 4; ++mi) {
#pragma unroll
      for (int r = 0; r < 4; ++r) {
        int s = mi * 16 + (lane >> 4) * 4 + r;
        float mv = 0.f;
        if (s <= t) mv = acc1[mi][r] * __expf(la_t - sLa[s]) * sDt[s];
        sM[t][s] = (bf16_t)mv;
      }
    }
  }

  // GEMM3: Tc[p, n-tile w] = X^T @ Bw  (independent of M writes)
  f32x4 acc3[4] = {};
#pragma unroll
  for (int k0 = 0; k0 < 64; k0 += 32) {
    bf16x8 bv = *(const bf16x8*)&sBwt[w * 16 + fr][k0 + fk];
#pragma unroll
    for (int mi = 0; mi < 4; ++mi) {
      bf16x8 av = *(const bf16x8*)&sXt[mi * 16 + fr][k0 + fk];
      acc3[mi] = __builtin_amdgcn_mfma_f32_16x16x32_bf16(av, bv, acc3[mi], 0, 0, 0);
    }
  }
  __syncthreads();   // M visible

  // GEMM2: Y[t, p-tile w] = M @ X
  f32x4 acc2[4] = {};
  {
    bf16_t (*sM)[72] = sB;
#pragma unroll
    for (int k0 = 0; k0 < 64; k0 += 32) {
      bf16x8 bv = *(const bf16x8*)&sXt[w * 16 + fr][k0 + fk];
#pragma unroll
      for (int mi = 0; mi < 4; ++mi) {
        bf16x8 av = *(const bf16x8*)&sM[mi * 16 + fr][k0 + fk];
        acc2[mi] = __builtin_amdgcn_mfma_f32_16x16x32_bf16(av, bv, acc2[mi], 0, 0, 0);
      }
    }
  }

  // stores
  bf16_t* yout = y2 + (size_t)dir * NROWS * D_INNER;
  bf16_t* tco = Tc_buf + (size_t)bid * 4096;
#pragma unroll
  for (int mi = 0; mi < 4; ++mi) {
#pragma unroll
    for (int r = 0; r < 4; ++r) {
      int rowl = mi * 16 + (lane >> 4) * 4 + r;
      int coll = w * 16 + fr;
      yout[ROWOF(rowl) * D_INNER + h * 64 + coll] = (bf16_t)acc2[mi][r];
      tco[rowl * 64 + coll] = (bf16_t)acc3[mi][r];
    }
  }
#undef ROWOF
}

// ---------------- K2a: parallel state prefix, in-place Tc -> S ----------------
// grid = 512: g = bid>>1 (dir*128+b*16+h), part = bid&1. 256 thr x 8 elems.
__global__ __launch_bounds__(256) void state_prefix_kernel(
    const float* __restrict__ la_buf, bf16_t* __restrict__ Tc_buf) {
  const int g = blockIdx.x >> 1;
  const int e0 = (blockIdx.x & 1) * 2048 + threadIdx.x * 8;
  bf16_t* tc = Tc_buf + (size_t)g * 32 * 4096 + e0;
  const float* la63 = la_buf + (size_t)g * 32 * 64 + 63;
  float S[8] = {};
  for (int cc = 0; cc < 32; ++cc) {
    bf16x8 t = *(const bf16x8*)(tc + (size_t)cc * 4096);
    float d = __expf(la63[cc * 64]);
    bf16_t sb[8];
#pragma unroll
    for (int j = 0; j < 8; ++j) sb[j] = (bf16_t)S[j];
    *(bf16x8*)(tc + (size_t)cc * 4096) = *(bf16x8*)sb;
    const bf16_t* tp = (const bf16_t*)&t;
#pragma unroll
    for (int j = 0; j < 8; ++j) S[j] = d * S[j] + (float)tp[j];
  }
}

// ---------------- K2b: Y_state apply (2048 blocks, vectorized, bf16 xbc) ----------------
__global__ __launch_bounds__(256) void ystate_kernel(
    const bf16_t* __restrict__ xbc, const bf16_t* __restrict__ S_buf,
    const float* __restrict__ la_buf, bf16_t* __restrict__ y2) {
  const int bid = blockIdx.x;
  const int hg = bid & 3, c = (bid >> 2) & 31, b = (bid >> 7) & 7, dir = bid >> 10;
  const int tid = threadIdx.x, w = tid >> 6, lane = tid & 63;
  const int fr = lane & 15, fk = (lane >> 4) * 8;
  const size_t base = (size_t)b * L_SEQ;

  __shared__ __align__(16) bf16_t sC[64][72];   // C rows, bf16, padded
  __shared__ __align__(16) float  sYf[64][72];  // f32 bounce for vectorized RMW
  __shared__ float sEla[64];

  // ---- stage C tile once: pure bf16x8 copy (512 units) ----
#pragma unroll
  for (int uu = 0; uu < 2; ++uu) {
    int u = tid + uu * 256;          // 0..511
    int row = u >> 3, q = u & 7;     // 64 rows x 8 units of 8 bf16
    int t = c * 64 + row;
    int tr = dir ? (L_SEQ - 1 - t) : t;
    bf16x8 cv = *(const bf16x8*)(xbc + (base + tr) * CONV_DIM + D_INNER + D_STATE + q * 8);
    *(bf16x8*)&sC[row][q * 8] = cv;
  }
  __syncthreads();

  bf16_t* yout = y2 + (size_t)dir * NROWS * D_INNER;

#pragma unroll 1
  for (int hi = 0; hi < 4; ++hi) {
    const int h = hg * 4 + hi;
    const int bidh = dir * 4096 + b * 512 + h * 32 + c;   // original (c,h,b,dir) block id
    if (tid < 64) sEla[tid] = __expf(la_buf[(size_t)bidh * 64 + tid]);

    const bf16_t* Sp = S_buf + (size_t)bidh * 4096;
    f32x4 acc[4] = {};
#pragma unroll
    for (int k0 = 0; k0 < 64; k0 += 32) {
      bf16x8 bv = *(const bf16x8*)(Sp + (w * 16 + fr) * 64 + k0 + fk);
#pragma unroll
      for (int mi = 0; mi < 4; ++mi) {
        bf16x8 av = *(const bf16x8*)&sC[mi * 16 + fr][k0 + fk];
        acc[mi] = __builtin_amdgcn_mfma_f32_16x16x32_bf16(av, bv, acc[mi], 0, 0, 0);
      }
    }
    __syncthreads();   // sEla ready; previous head's sYf fully consumed

    // scale by exp(la) and drop into f32 bounce buffer
#pragma unroll
    for (int mi = 0; mi < 4; ++mi) {
#pragma unroll
      for (int r = 0; r < 4; ++r) {
        int tl = mi * 16 + (lane >> 4) * 4 + r;
        sYf[tl][w * 16 + fr] = acc[mi][r] * sEla[tl];
      }
    }
    __syncthreads();

    // vectorized RMW: 512 units of 8 consecutive bf16; 2 per thread
#pragma unroll
    for (int uu = 0; uu < 2; ++uu) {
      int u = tid + uu * 256;
      int row = u >> 3, oct = u & 7;
      int t = c * 64 + row;
      int tr = dir ? (L_SEQ - 1 - t) : t;
      bf16_t* gp = yout + (base + tr) * D_INNER + h * 64 + oct * 8;
      bf16x8 old = *(const bf16x8*)gp;
      const float* yp = &sYf[row][oct * 8];
      bf16x8 nw;
#pragma unroll
      for (int j = 0; j < 8; ++j) nw[j] = (bf16_t)((float)old[j] + yp[j]);
      *(bf16x8*)gp = nw;
    }
  }
}

// ---------------- combine: y = rmsnorm((yf+yb+D*xs) * silu(z)) * norm_w -> bf16 ----------------
__global__ __launch_bounds__(256) void combine_kernel(
    const bf16_t* __restrict__ y2, const bf16_t* __restrict__ xbc_conv,
    const float* __restrict__ z, const float* __restrict__ Dp,
    const float* __restrict__ norm_w, bf16_t* __restrict__ yn) {
  __shared__ float red[4];
  int row = blockIdx.x;
  int c0 = threadIdx.x * 4;
  const bf16_t* yf = y2 + (size_t)row * D_INNER;
  const bf16_t* yb = y2 + (size_t)NROWS * D_INNER + (size_t)row * D_INNER;
  const bf16_t* xs = xbc_conv + (size_t)row * CONV_DIM;
  const float* zr = z + (size_t)row * D_INNER;

  bf16x4 vf = *(const bf16x4*)&yf[c0];
  bf16x4 vb = *(const bf16x4*)&yb[c0];
  bf16x4 vx = *(const bf16x4*)&xs[c0];
  f32x4 vz = *(const f32x4*)&zr[c0];
  float Dh = Dp[c0 >> 6];

  float g[4];
  float ss = 0.f;
#pragma unroll
  for (int j = 0; j < 4; ++j) {
    float v = (float)vf[j] + (float)vb[j] + Dh * (float)vx[j];
    float gg = v * silu_f(vz[j]);
    g[j] = gg;
    ss += gg * gg;
  }
  ss = block_sum256(ss, red);
  float r = rsqrtf(ss * (1.f / 1024.f) + EPS);
  bf16x4 o;
#pragma unroll
  for (int j = 0; j < 4; ++j) o[j] = (bf16_t)(g[j] * r * norm_w[c0 + j]);
  *(bf16x4*)&yn[(size_t)row * D_INNER + c0] = o;
}

// ---------------- launcher ----------------
extern "C" void kernel_launch(void* const* d_in, const int* in_sizes, int n_in,
                              void* d_out, int out_size, void* d_ws, size_t ws_size,
                              hipStream_t stream) {
  const float* x       = (const float*)d_in[0];
  const float* mask    = (const float*)d_in[1];
  const float* W_in    = (const float*)d_in[2];
  const float* conv_w  = (const float*)d_in[3];
  const float* conv_b  = (const float*)d_in[4];
  const float* dt_bias = (const float*)d_in[5];
  const float* A_log   = (const float*)d_in[6];
  const float* Dp      = (const float*)d_in[7];
  const float* norm_w  = (const float*)d_in[8];
  const float* W_out   = (const float*)d_in[9];
  const float* W1      = (const float*)d_in[10];
  const float* b1      = (const float*)d_in[11];
  const float* W2      = (const float*)d_in[12];
  const float* b2      = (const float*)d_in[13];

  float* out_x  = (float*)d_out;                       // 16384*512
  float* out_m  = out_x + (size_t)NROWS * 512;         // 16384*512
  float* out_dt = out_m + (size_t)NROWS * 512;         // 16384*16
  float* out_z  = out_dt + (size_t)NROWS * NHEADS;     // 16384*1024

  char* ws = (char*)d_ws;
  bf16_t* wt_in    = (bf16_t*)(ws + OFF_WT_IN);
  bf16_t* wt_out   = (bf16_t*)(ws + OFF_WT_OUT);
  bf16_t* w1t      = (bf16_t*)(ws + OFF_W1T);
  bf16_t* w2t      = (bf16_t*)(ws + OFF_W2T);
  bf16_t* u_bf     = (bf16_t*)(ws + OFF_U);            // reused: la_buf (scan), h_bf (ffn)
  bf16_t* xbc_bf   = (bf16_t*)(ws + OFF_XBC_RAW);      // bf16 xBC raw; reused: Tc/S_buf, gelu later
  bf16_t* xbc_conv = (bf16_t*)(ws + OFF_XBC_CONV);
  bf16_t* y2       = (bf16_t*)(ws + OFF_Y2);
  bf16_t* yn       = (bf16_t*)(ws + OFF_YN);
  bf16_t* h_bf     = u_bf;
  bf16_t* gelu_bf  = (bf16_t*)(ws + OFF_XBC_RAW);
  bf16_t* Tc_buf   = (bf16_t*)(ws + OFF_XBC_RAW);      // 8192*4096 bf16 = 67 MB <= 75 MB region
  float*  la_buf   = (float*)(ws + OFF_U);             // 8192*64 f32 = 2 MB <= 16.7 MB region

  // 1. weights -> bf16 transposed (tiled transpose, coalesced both sides)
  transpose_cast_kernel<<<dim3(69, 16), 256, 0, stream>>>(W_in, wt_in, 512, D_IN_PROJ);
  transpose_cast_kernel<<<dim3(16, 32), 256, 0, stream>>>(W_out, wt_out, 1024, 512);
  transpose_cast_kernel<<<dim3(64, 16), 256, 0, stream>>>(W1, w1t, 512, 2048);
  transpose_cast_kernel<<<dim3(16, 64), 256, 0, stream>>>(W2, w2t, 2048, 512);
  // 2. u = rmsnorm(x*mask)
  rmsnorm_in_kernel<<<NROWS, 256, 0, stream>>>(x, mask, u_bf);
  // 3. zxbcdt = u @ W_in, split into z / xBC(bf16) / dt(softplus)
  gemm_kernel<1><<<dim3(18, 128), 256, 0, stream>>>(u_bf, wt_in, NROWS, D_IN_PROJ, 512,
                                                    out_z, nullptr, out_dt, xbc_bf, dt_bias, nullptr);
  // 4. conv1d + silu + mask -> bf16
  conv_silu_kernel<<<NROWS, 320, 0, stream>>>(xbc_bf, conv_w, conv_b, mask, xbc_conv);
  // 5a. SSD chunked scan: per-chunk GEMMs (Y_intra, Tc, la)
  scan_chunk_kernel<<<8192, 256, 0, stream>>>(xbc_conv, out_dt, A_log, y2, Tc_buf, la_buf);
  // 5b. parallel state prefix (in-place Tc -> S)
  state_prefix_kernel<<<512, 256, 0, stream>>>(la_buf, Tc_buf);
  // 5c. Y_state apply (vectorized MFMA + LDS-bounced 16B RMW)
  ystate_kernel<<<2048, 256, 0, stream>>>(xbc_conv, Tc_buf, la_buf, y2);
  // 6. combine + gated rmsnorm
  combine_kernel<<<NROWS, 256, 0, stream>>>(y2, xbc_conv, out_z, Dp, norm_w, yn);
  // 7. m = yn @ W_out
  gemm_kernel<0><<<dim3(4, 128), 256, 0, stream>>>(yn, wt_out, NROWS, 512, 1024,
                                                   out_m, nullptr, nullptr, nullptr, nullptr, nullptr);
  // 8. h = rmsnorm(2m)
  rmsnorm2_kernel<<<NROWS, 256, 0, stream>>>(out_m, h_bf);
  // 9. g = gelu(h @ W1 + b1)
  gemm_kernel<2><<<dim3(16, 128), 256, 0, stream>>>(h_bf, w1t, NROWS, D_FF, 512,
                                                    nullptr, nullptr, nullptr, gelu_bf, b1, nullptr);
  // 10. x = 2m + g @ W2 + b2
  gemm_kernel<3><<<dim3(4, 128), 256, 0, stream>>>(gelu_bf, w2t, NROWS, 512, D_FF,
                                                   out_x, nullptr, nullptr, nullptr, b2, out_m);
}

// Round 7
// 622.694 us; speedup vs baseline: 1.0942x; 1.0029x over previous
//
#include <hip/hip_runtime.h>
#include <cstdint>
#include <cstddef>

// ---------------- constants ----------------
#define L_SEQ   2048
#define NROWS   16384            // B*L = 8*2048
#define D_MODEL 512
#define D_INNER 1024
#define D_STATE 64
#define NHEADS  16
#define CONV_DIM 1152
#define D_IN_PROJ 2192
#define D_FF 2048
#define EPS 1e-6f

typedef __bf16 bf16_t;
typedef __bf16 bf16x8 __attribute__((ext_vector_type(8)));
typedef __bf16 bf16x4 __attribute__((ext_vector_type(4)));
typedef float  f32x4  __attribute__((ext_vector_type(4)));

// workspace layout (bytes)
#define OFF_WT_IN    0ull                       // 2192*512 bf16  = 2,244,608
#define OFF_WT_OUT   2244608ull                 // 512*1024 bf16  = 1,048,576
#define OFF_W1T      3293184ull                 // 2048*512 bf16  = 2,097,152
#define OFF_W2T      5390336ull                 // 512*2048 bf16  = 2,097,152
#define OFF_U        7487488ull                 // 16384*512 bf16 (u_bf; reused: la_buf during scan, h_bf later)
#define OFF_XBC_RAW  24264704ull                // 16384*1152 bf16 (xbc_bf; reused: Tc/S_buf during scan, gelu bf16 later)
#define OFF_XBC_CONV 99762176ull                // 16384*1152 bf16
#define OFF_Y2       175259648ull               // 2*16384*1024 bf16 = 67,108,864
#define OFF_YN       242368512ull               // 16384*1024 bf16 = 33,554,432
// total ~276 MB

// ---------------- helpers ----------------
__device__ __forceinline__ void gl_lds16(const void* g, void* s) {
  __builtin_amdgcn_global_load_lds(
      (__attribute__((address_space(1))) void*)(void*)g,
      (__attribute__((address_space(3))) void*)s, 16, 0, 0);
}

__device__ __forceinline__ float block_sum256(float v, float* red) {
#pragma unroll
  for (int o = 32; o > 0; o >>= 1) v += __shfl_xor(v, o, 64);
  int w = threadIdx.x >> 6;
  if ((threadIdx.x & 63) == 0) red[w] = v;
  __syncthreads();
  return red[0] + red[1] + red[2] + red[3];
}

__device__ __forceinline__ float softplus_f(float x) {
  return (x > 20.f) ? x : log1pf(expf(x));
}
__device__ __forceinline__ float silu_f(float x) {
  return x / (1.f + expf(-x));
}
__device__ __forceinline__ float gelu_tanh_f(float x) {
  float x3 = x * x * x;
  return 0.5f * x * (1.f + tanhf(0.7978845608f * (x + 0.044715f * x3)));
}

// ---------------- weight prep v2: LDS 32x32 tile transpose, f32 -> bf16 ----------------
// dst[c][r] = src[r][c]; src is R x C row-major f32, dst is C x R row-major bf16.
__global__ __launch_bounds__(256) void transpose_cast_kernel(
    const float* __restrict__ src, bf16_t* __restrict__ dst, int R, int C) {
  __shared__ float tile[32][33];
  const int tx = threadIdx.x & 31;
  const int ty = threadIdx.x >> 5;          // 0..7
  const int r0 = blockIdx.y * 32;
  const int c0 = blockIdx.x * 32;
#pragma unroll
  for (int j = 0; j < 4; ++j) {
    int r = r0 + ty + j * 8;
    int c = c0 + tx;
    if (r < R && c < C) tile[ty + j * 8][tx] = src[(size_t)r * C + c];
  }
  __syncthreads();
#pragma unroll
  for (int j = 0; j < 4; ++j) {
    int c = c0 + ty + j * 8;
    int r = r0 + tx;
    if (c < C && r < R) dst[(size_t)c * R + r] = (bf16_t)tile[tx][ty + j * 8];
  }
}

// ---------------- rmsnorm of masked input -> bf16 ----------------
__global__ __launch_bounds__(256) void rmsnorm_in_kernel(
    const float* __restrict__ x, const float* __restrict__ mask,
    bf16_t* __restrict__ u) {
  __shared__ float red[4];
  int row = blockIdx.x;
  float mk = mask[row];
  const float* xr = x + (size_t)row * 512;
  float v0 = xr[threadIdx.x] * mk;
  float v1 = xr[threadIdx.x + 256] * mk;
  float ss = block_sum256(v0 * v0 + v1 * v1, red);
  float r = rsqrtf(ss * (1.f / 512.f) + EPS);
  bf16_t* ur = u + (size_t)row * 512;
  ur[threadIdx.x] = (bf16_t)(v0 * r);
  ur[threadIdx.x + 256] = (bf16_t)(v1 * r);
}

// ---------------- rmsnorm of 2*m -> bf16 ----------------
__global__ __launch_bounds__(256) void rmsnorm2_kernel(
    const float* __restrict__ m, bf16_t* __restrict__ h) {
  __shared__ float red[4];
  int row = blockIdx.x;
  const float* mr = m + (size_t)row * 512;
  float v0 = 2.f * mr[threadIdx.x];
  float v1 = 2.f * mr[threadIdx.x + 256];
  float ss = block_sum256(v0 * v0 + v1 * v1, red);
  float r = rsqrtf(ss * (1.f / 512.f) + EPS);
  bf16_t* hr = h + (size_t)row * 512;
  hr[threadIdx.x] = (bf16_t)(v0 * r);
  hr[threadIdx.x + 256] = (bf16_t)(v1 * r);
}

// ---------------- MFMA GEMM: C[M,N] = A[M,K](bf16) @ Bt[N,K](bf16)^T ----------------
// v6: v5 + XCD-aware chunk swizzle (T1): each XCD gets a contiguous run of work-ids
//     (x fastest within chunk) so A-slabs + full B stay L2-resident per XCD.
//     Requires nwg % 8 == 0 (all four grids: 2304/512/2048/512).
template <int EPI>
__global__ __launch_bounds__(256, 4) void gemm_kernel(
    const bf16_t* __restrict__ A, const bf16_t* __restrict__ Bt,
    int M, int N, int K,
    float* __restrict__ o0, float* __restrict__ o1, float* __restrict__ o2,
    bf16_t* __restrict__ ob, const float* __restrict__ bias,
    const float* __restrict__ extra) {
  __shared__ bf16_t As[2][128 * 32];
  __shared__ bf16_t Bs[2][128 * 32];
  const int tid = threadIdx.x;
  const int lane = tid & 63;
  const int w = tid >> 6;

  const int nx = gridDim.x;
  const int nwg = nx * gridDim.y;
  const int lin = blockIdx.y * nx + blockIdx.x;
  const int wid = (lin & 7) * (nwg >> 3) + (lin >> 3);   // bijective when nwg%8==0
  const int tileM = (wid / nx) * 128;
  const int tileN = (wid % nx) * 128;

  f32x4 acc[4][4] = {};

  const int wm = (w >> 1) * 64;
  const int wn = (w & 1) * 64;
  const int fr = lane & 15;
  const int fk = (lane >> 4) * 8;

  const int rsub = lane >> 2;                  // row-within-16 of this lane's 16B chunk
  const int cb   = (lane & 3) * 16;            // byte col within 64B row

  auto stage = [&](int buf, int k0) {
#pragma unroll
    for (int i = 0; i < 2; ++i) {
      int rloc = w * 32 + i * 16 + rsub;
      const char* ga = (const char*)(A + (size_t)(tileM + rloc) * K + k0) + cb;
      gl_lds16(ga, (void*)&As[buf][(w * 32 + i * 16) * 32]);
      int rn = tileN + rloc;
      if (rn >= N) rn = N - 1;
      const char* gb = (const char*)(Bt + (size_t)rn * K + k0) + cb;
      gl_lds16(gb, (void*)&Bs[buf][(w * 32 + i * 16) * 32]);
    }
  };

  const int nt = K >> 5;
  stage(0, 0);
  __syncthreads();
  int cur = 0;
  for (int t = 0; t < nt; ++t) {
    if (t + 1 < nt) stage(cur ^ 1, (t + 1) << 5);

    bf16x8 av[4], bv[4];
#pragma unroll
    for (int i = 0; i < 4; ++i)
      av[i] = *(const bf16x8*)&As[cur][(wm + i * 16 + fr) * 32 + fk];
#pragma unroll
    for (int j = 0; j < 4; ++j)
      bv[j] = *(const bf16x8*)&Bs[cur][(wn + j * 16 + fr) * 32 + fk];
#pragma unroll
    for (int i = 0; i < 4; ++i)
#pragma unroll
      for (int j = 0; j < 4; ++j)
        acc[i][j] = __builtin_amdgcn_mfma_f32_16x16x32_bf16(av[i], bv[j], acc[i][j], 0, 0, 0);

    __syncthreads();
    cur ^= 1;
  }

  // -------- epilogue --------
  const int cn = lane & 15;
  const int r0 = (lane >> 4) * 4;
#pragma unroll
  for (int i = 0; i < 4; ++i) {
#pragma unroll
    for (int j = 0; j < 4; ++j) {
      int gn = tileN + wn + j * 16 + cn;
      if (gn >= N) continue;
#pragma unroll
      for (int r = 0; r < 4; ++r) {
        int gm = tileM + wm + i * 16 + r0 + r;
        float v = acc[i][j][r];
        if (EPI == 0) {
          o0[(size_t)gm * N + gn] = v;
        } else if (EPI == 1) {
          if (gn < D_INNER) {
            o0[(size_t)gm * D_INNER + gn] = v;                       // z (f32 output)
          } else if (gn < D_INNER + CONV_DIM) {
            ob[(size_t)gm * CONV_DIM + (gn - D_INNER)] = (bf16_t)v;  // xBC raw -> bf16
          } else {
            int hh = gn - (D_INNER + CONV_DIM);
            o2[(size_t)gm * NHEADS + hh] = softplus_f(v + bias[hh]); // dt
          }
        } else if (EPI == 2) {
          ob[(size_t)gm * N + gn] = (bf16_t)gelu_tanh_f(v + bias[gn]);
        } else if (EPI == 3) {
          o0[(size_t)gm * N + gn] = v + bias[gn] + 2.f * extra[(size_t)gm * N + gn];
        }
      }
    }
  }
}

// ---------------- causal conv1d (k=4) + silu + mask: bf16 in -> bf16 out ----------------
__global__ __launch_bounds__(320) void conv_silu_kernel(
    const bf16_t* __restrict__ xbc_raw, const float* __restrict__ conv_w,
    const float* __restrict__ conv_b, const float* __restrict__ mask,
    bf16_t* __restrict__ xbc_conv) {
  int row = blockIdx.x;
  int tid = threadIdx.x;
  if (tid >= 288) return;
  int t = row & (L_SEQ - 1);
  float mk = mask[row];
  int c = tid * 4;
  const bf16_t* base = xbc_raw + (size_t)row * CONV_DIM + c;
  bf16x4 z4 = {};
  bf16x4 r0 = *(const bf16x4*)base;
  bf16x4 r1 = (t >= 1) ? *(const bf16x4*)(base - CONV_DIM) : z4;
  bf16x4 r2 = (t >= 2) ? *(const bf16x4*)(base - 2 * CONV_DIM) : z4;
  bf16x4 r3 = (t >= 3) ? *(const bf16x4*)(base - 3 * CONV_DIM) : z4;
  bf16x4 o;
#pragma unroll
  for (int j = 0; j < 4; ++j) {
    float4 wv = ((const float4*)conv_w)[c + j];   // conv_w[c+j][0..3]
    float acc = conv_b[c + j] + wv.x * (float)r3[j] + wv.y * (float)r2[j] +
                wv.z * (float)r1[j] + wv.w * (float)r0[j];
    o[j] = (bf16_t)(silu_f(acc) * mk);
  }
  *(bf16x4*)&xbc_conv[(size_t)row * CONV_DIM + c] = o;
}

// ================= SSD chunked scan =================

// ---------------- K1: per-chunk parallel kernel (8192 blocks) ----------------
// v2: h-fastest decode + XCD chunk swizzle: the 16 head-blocks sharing identical
//     B/C/dt rows run consecutively on one XCD (L2 reuse). Buffer layout (la/Tc)
//     keeps the original sid = dir*4096 + b*512 + h*32 + c indexing.
__global__ __launch_bounds__(256) void scan_chunk_kernel(
    const bf16_t* __restrict__ xbc, const float* __restrict__ dt_all,
    const float* __restrict__ A_log,
    bf16_t* __restrict__ y2, bf16_t* __restrict__ Tc_buf,
    float* __restrict__ la_buf) {
  const int lin = blockIdx.x;
  const int wid = (lin & 7) * 1024 + (lin >> 3);           // 8192/8 = 1024 per XCD
  const int h = wid & 15, c = (wid >> 4) & 31, b = (wid >> 9) & 7, dir = wid >> 12;
  const int sid = dir * 4096 + b * 512 + h * 32 + c;       // storage id (consumer layout)
  const float A_h = -expf(A_log[h]);
  const int tid = threadIdx.x, w = tid >> 6, lane = tid & 63;
  const int fr = lane & 15, fk = (lane >> 4) * 8;

  __shared__ __align__(16) bf16_t sB[64][72];    // B rows [s][n]; aliased as M[t][s] later
  __shared__ __align__(16) bf16_t sC[64][72];    // C rows [t][n]
  __shared__ __align__(16) bf16_t sXt[64][72];   // X^T [p][s]
  __shared__ __align__(16) bf16_t sBwt[64][72];  // (w.B)^T [n][s]
  __shared__ float sLa[64], sDt[64], sW[64];

  const size_t base = (size_t)b * L_SEQ;
#define ROWOF(i) (base + (size_t)(dir ? (L_SEQ - 1 - (c * 64 + (i))) : (c * 64 + (i))))

  if (tid < 64) sDt[tid] = dt_all[ROWOF(tid) * NHEADS + h];

  float bB[16];
#pragma unroll
  for (int r = 0; r < 16; ++r) {
    int i = w * 16 + r;
    const bf16_t* src = xbc + ROWOF(i) * CONV_DIM;
    bf16_t xv = src[h * 64 + lane];
    bf16_t bv = src[D_INNER + lane];
    bf16_t cv = src[D_INNER + D_STATE + lane];
    bB[r] = (float)bv;
    sB[i][lane] = bv;
    sC[i][lane] = cv;
    sXt[lane][i] = xv;
  }
  __syncthreads();

  if (w == 0) {
    float v = sDt[lane] * A_h;
#pragma unroll
    for (int d = 1; d < 64; d <<= 1) {
      float o = __shfl_up(v, d, 64);
      if (lane >= d) v += o;
    }
    sLa[lane] = v;
    float la63 = __shfl(v, 63, 64);
    sW[lane] = __expf(la63 - v) * sDt[lane];
  }
  __syncthreads();

  // weighted-transposed B, and la out
#pragma unroll
  for (int r = 0; r < 16; ++r) {
    int i = w * 16 + r;
    sBwt[lane][i] = (bf16_t)(bB[r] * sW[i]);
  }
  if (tid < 64) la_buf[(size_t)sid * 64 + tid] = sLa[tid];

  // GEMM1: Gt[s, t-tile w] = B @ C^T (skip all-zero upper s-tiles: mi > w)
  f32x4 acc1[4] = {};
#pragma unroll
  for (int k0 = 0; k0 < 64; k0 += 32) {
    bf16x8 bv = *(const bf16x8*)&sC[w * 16 + fr][k0 + fk];
#pragma unroll
    for (int mi = 0; mi < 4; ++mi) {
      if (mi <= w) {
        bf16x8 av = *(const bf16x8*)&sB[mi * 16 + fr][k0 + fk];
        acc1[mi] = __builtin_amdgcn_mfma_f32_16x16x32_bf16(av, bv, acc1[mi], 0, 0, 0);
      }
    }
  }
  __syncthreads();   // GEMM1 reads done (sB can be overwritten); sBwt visible

  // build M[t][s] into sB alias
  {
    bf16_t (*sM)[72] = sB;
    float la_t = sLa[w * 16 + fr];
    int t = w * 16 + fr;
#pragma unroll
    for (int mi = 0; mi < 4; ++mi) {
#pragma unroll
      for (int r = 0; r < 4; ++r) {
        int s = mi * 16 + (lane >> 4) * 4 + r;
        float mv = 0.f;
        if (s <= t) mv = acc1[mi][r] * __expf(la_t - sLa[s]) * sDt[s];
        sM[t][s] = (bf16_t)mv;
      }
    }
  }

  // GEMM3: Tc[p, n-tile w] = X^T @ Bw  (independent of M writes)
  f32x4 acc3[4] = {};
#pragma unroll
  for (int k0 = 0; k0 < 64; k0 += 32) {
    bf16x8 bv = *(const bf16x8*)&sBwt[w * 16 + fr][k0 + fk];
#pragma unroll
    for (int mi = 0; mi < 4; ++mi) {
      bf16x8 av = *(const bf16x8*)&sXt[mi * 16 + fr][k0 + fk];
      acc3[mi] = __builtin_amdgcn_mfma_f32_16x16x32_bf16(av, bv, acc3[mi], 0, 0, 0);
    }
  }
  __syncthreads();   // M visible

  // GEMM2: Y[t, p-tile w] = M @ X
  f32x4 acc2[4] = {};
  {
    bf16_t (*sM)[72] = sB;
#pragma unroll
    for (int k0 = 0; k0 < 64; k0 += 32) {
      bf16x8 bv = *(const bf16x8*)&sXt[w * 16 + fr][k0 + fk];
#pragma unroll
      for (int mi = 0; mi < 4; ++mi) {
        bf16x8 av = *(const bf16x8*)&sM[mi * 16 + fr][k0 + fk];
        acc2[mi] = __builtin_amdgcn_mfma_f32_16x16x32_bf16(av, bv, acc2[mi], 0, 0, 0);
      }
    }
  }

  // stores
  bf16_t* yout = y2 + (size_t)dir * NROWS * D_INNER;
  bf16_t* tco = Tc_buf + (size_t)sid * 4096;
#pragma unroll
  for (int mi = 0; mi < 4; ++mi) {
#pragma unroll
    for (int r = 0; r < 4; ++r) {
      int rowl = mi * 16 + (lane >> 4) * 4 + r;
      int coll = w * 16 + fr;
      yout[ROWOF(rowl) * D_INNER + h * 64 + coll] = (bf16_t)acc2[mi][r];
      tco[rowl * 64 + coll] = (bf16_t)acc3[mi][r];
    }
  }
#undef ROWOF
}

// ---------------- K2a: parallel state prefix, in-place Tc -> S ----------------
// grid = 512: g = bid>>1 (dir*128+b*16+h), part = bid&1. 256 thr x 8 elems.
__global__ __launch_bounds__(256) void state_prefix_kernel(
    const float* __restrict__ la_buf, bf16_t* __restrict__ Tc_buf) {
  const int g = blockIdx.x >> 1;
  const int e0 = (blockIdx.x & 1) * 2048 + threadIdx.x * 8;
  bf16_t* tc = Tc_buf + (size_t)g * 32 * 4096 + e0;
  const float* la63 = la_buf + (size_t)g * 32 * 64 + 63;
  float S[8] = {};
  for (int cc = 0; cc < 32; ++cc) {
    bf16x8 t = *(const bf16x8*)(tc + (size_t)cc * 4096);
    float d = __expf(la63[cc * 64]);
    bf16_t sb[8];
#pragma unroll
    for (int j = 0; j < 8; ++j) sb[j] = (bf16_t)S[j];
    *(bf16x8*)(tc + (size_t)cc * 4096) = *(bf16x8*)sb;
    const bf16_t* tp = (const bf16_t*)&t;
#pragma unroll
    for (int j = 0; j < 8; ++j) S[j] = d * S[j] + (float)tp[j];
  }
}

// ---------------- K2b: Y_state apply (2048 blocks, vectorized, bf16 xbc) ----------------
__global__ __launch_bounds__(256) void ystate_kernel(
    const bf16_t* __restrict__ xbc, const bf16_t* __restrict__ S_buf,
    const float* __restrict__ la_buf, bf16_t* __restrict__ y2) {
  const int bid = blockIdx.x;
  const int hg = bid & 3, c = (bid >> 2) & 31, b = (bid >> 7) & 7, dir = bid >> 10;
  const int tid = threadIdx.x, w = tid >> 6, lane = tid & 63;
  const int fr = lane & 15, fk = (lane >> 4) * 8;
  const size_t base = (size_t)b * L_SEQ;

  __shared__ __align__(16) bf16_t sC[64][72];   // C rows, bf16, padded
  __shared__ __align__(16) float  sYf[64][72];  // f32 bounce for vectorized RMW
  __shared__ float sEla[64];

  // ---- stage C tile once: pure bf16x8 copy (512 units) ----
#pragma unroll
  for (int uu = 0; uu < 2; ++uu) {
    int u = tid + uu * 256;          // 0..511
    int row = u >> 3, q = u & 7;     // 64 rows x 8 units of 8 bf16
    int t = c * 64 + row;
    int tr = dir ? (L_SEQ - 1 - t) : t;
    bf16x8 cv = *(const bf16x8*)(xbc + (base + tr) * CONV_DIM + D_INNER + D_STATE + q * 8);
    *(bf16x8*)&sC[row][q * 8] = cv;
  }
  __syncthreads();

  bf16_t* yout = y2 + (size_t)dir * NROWS * D_INNER;

#pragma unroll 1
  for (int hi = 0; hi < 4; ++hi) {
    const int h = hg * 4 + hi;
    const int bidh = dir * 4096 + b * 512 + h * 32 + c;   // original (c,h,b,dir) block id
    if (tid < 64) sEla[tid] = __expf(la_buf[(size_t)bidh * 64 + tid]);

    const bf16_t* Sp = S_buf + (size_t)bidh * 4096;
    f32x4 acc[4] = {};
#pragma unroll
    for (int k0 = 0; k0 < 64; k0 += 32) {
      bf16x8 bv = *(const bf16x8*)(Sp + (w * 16 + fr) * 64 + k0 + fk);
#pragma unroll
      for (int mi = 0; mi < 4; ++mi) {
        bf16x8 av = *(const bf16x8*)&sC[mi * 16 + fr][k0 + fk];
        acc[mi] = __builtin_amdgcn_mfma_f32_16x16x32_bf16(av, bv, acc[mi], 0, 0, 0);
      }
    }
    __syncthreads();   // sEla ready; previous head's sYf fully consumed

    // scale by exp(la) and drop into f32 bounce buffer
#pragma unroll
    for (int mi = 0; mi < 4; ++mi) {
#pragma unroll
      for (int r = 0; r < 4; ++r) {
        int tl = mi * 16 + (lane >> 4) * 4 + r;
        sYf[tl][w * 16 + fr] = acc[mi][r] * sEla[tl];
      }
    }
    __syncthreads();

    // vectorized RMW: 512 units of 8 consecutive bf16; 2 per thread
#pragma unroll
    for (int uu = 0; uu < 2; ++uu) {
      int u = tid + uu * 256;
      int row = u >> 3, oct = u & 7;
      int t = c * 64 + row;
      int tr = dir ? (L_SEQ - 1 - t) : t;
      bf16_t* gp = yout + (base + tr) * D_INNER + h * 64 + oct * 8;
      bf16x8 old = *(const bf16x8*)gp;
      const float* yp = &sYf[row][oct * 8];
      bf16x8 nw;
#pragma unroll
      for (int j = 0; j < 8; ++j) nw[j] = (bf16_t)((float)old[j] + yp[j]);
      *(bf16x8*)gp = nw;
    }
  }
}

// ---------------- combine: y = rmsnorm((yf+yb+D*xs) * silu(z)) * norm_w -> bf16 ----------------
__global__ __launch_bounds__(256) void combine_kernel(
    const bf16_t* __restrict__ y2, const bf16_t* __restrict__ xbc_conv,
    const float* __restrict__ z, const float* __restrict__ Dp,
    const float* __restrict__ norm_w, bf16_t* __restrict__ yn) {
  __shared__ float red[4];
  int row = blockIdx.x;
  int c0 = threadIdx.x * 4;
  const bf16_t* yf = y2 + (size_t)row * D_INNER;
  const bf16_t* yb = y2 + (size_t)NROWS * D_INNER + (size_t)row * D_INNER;
  const bf16_t* xs = xbc_conv + (size_t)row * CONV_DIM;
  const float* zr = z + (size_t)row * D_INNER;

  bf16x4 vf = *(const bf16x4*)&yf[c0];
  bf16x4 vb = *(const bf16x4*)&yb[c0];
  bf16x4 vx = *(const bf16x4*)&xs[c0];
  f32x4 vz = *(const f32x4*)&zr[c0];
  float Dh = Dp[c0 >> 6];

  float g[4];
  float ss = 0.f;
#pragma unroll
  for (int j = 0; j < 4; ++j) {
    float v = (float)vf[j] + (float)vb[j] + Dh * (float)vx[j];
    float gg = v * silu_f(vz[j]);
    g[j] = gg;
    ss += gg * gg;
  }
  ss = block_sum256(ss, red);
  float r = rsqrtf(ss * (1.f / 1024.f) + EPS);
  bf16x4 o;
#pragma unroll
  for (int j = 0; j < 4; ++j) o[j] = (bf16_t)(g[j] * r * norm_w[c0 + j]);
  *(bf16x4*)&yn[(size_t)row * D_INNER + c0] = o;
}

// ---------------- launcher ----------------
extern "C" void kernel_launch(void* const* d_in, const int* in_sizes, int n_in,
                              void* d_out, int out_size, void* d_ws, size_t ws_size,
                              hipStream_t stream) {
  const float* x       = (const float*)d_in[0];
  const float* mask    = (const float*)d_in[1];
  const float* W_in    = (const float*)d_in[2];
  const float* conv_w  = (const float*)d_in[3];
  const float* conv_b  = (const float*)d_in[4];
  const float* dt_bias = (const float*)d_in[5];
  const float* A_log   = (const float*)d_in[6];
  const float* Dp      = (const float*)d_in[7];
  const float* norm_w  = (const float*)d_in[8];
  const float* W_out   = (const float*)d_in[9];
  const float* W1      = (const float*)d_in[10];
  const float* b1      = (const float*)d_in[11];
  const float* W2      = (const float*)d_in[12];
  const float* b2      = (const float*)d_in[13];

  float* out_x  = (float*)d_out;                       // 16384*512
  float* out_m  = out_x + (size_t)NROWS * 512;         // 16384*512
  float* out_dt = out_m + (size_t)NROWS * 512;         // 16384*16
  float* out_z  = out_dt + (size_t)NROWS * NHEADS;     // 16384*1024

  char* ws = (char*)d_ws;
  bf16_t* wt_in    = (bf16_t*)(ws + OFF_WT_IN);
  bf16_t* wt_out   = (bf16_t*)(ws + OFF_WT_OUT);
  bf16_t* w1t      = (bf16_t*)(ws + OFF_W1T);
  bf16_t* w2t      = (bf16_t*)(ws + OFF_W2T);
  bf16_t* u_bf     = (bf16_t*)(ws + OFF_U);            // reused: la_buf (scan), h_bf (ffn)
  bf16_t* xbc_bf   = (bf16_t*)(ws + OFF_XBC_RAW);      // bf16 xBC raw; reused: Tc/S_buf, gelu later
  bf16_t* xbc_conv = (bf16_t*)(ws + OFF_XBC_CONV);
  bf16_t* y2       = (bf16_t*)(ws + OFF_Y2);
  bf16_t* yn       = (bf16_t*)(ws + OFF_YN);
  bf16_t* h_bf     = u_bf;
  bf16_t* gelu_bf  = (bf16_t*)(ws + OFF_XBC_RAW);
  bf16_t* Tc_buf   = (bf16_t*)(ws + OFF_XBC_RAW);      // 8192*4096 bf16 = 67 MB <= 75 MB region
  float*  la_buf   = (float*)(ws + OFF_U);             // 8192*64 f32 = 2 MB <= 16.7 MB region

  // 1. weights -> bf16 transposed (tiled transpose, coalesced both sides)
  transpose_cast_kernel<<<dim3(69, 16), 256, 0, stream>>>(W_in, wt_in, 512, D_IN_PROJ);
  transpose_cast_kernel<<<dim3(16, 32), 256, 0, stream>>>(W_out, wt_out, 1024, 512);
  transpose_cast_kernel<<<dim3(64, 16), 256, 0, stream>>>(W1, w1t, 512, 2048);
  transpose_cast_kernel<<<dim3(16, 64), 256, 0, stream>>>(W2, w2t, 2048, 512);
  // 2. u = rmsnorm(x*mask)
  rmsnorm_in_kernel<<<NROWS, 256, 0, stream>>>(x, mask, u_bf);
  // 3. zxbcdt = u @ W_in, split into z / xBC(bf16) / dt(softplus)
  gemm_kernel<1><<<dim3(18, 128), 256, 0, stream>>>(u_bf, wt_in, NROWS, D_IN_PROJ, 512,
                                                    out_z, nullptr, out_dt, xbc_bf, dt_bias, nullptr);
  // 4. conv1d + silu + mask -> bf16
  conv_silu_kernel<<<NROWS, 320, 0, stream>>>(xbc_bf, conv_w, conv_b, mask, xbc_conv);
  // 5a. SSD chunked scan: per-chunk GEMMs (Y_intra, Tc, la)
  scan_chunk_kernel<<<8192, 256, 0, stream>>>(xbc_conv, out_dt, A_log, y2, Tc_buf, la_buf);
  // 5b. parallel state prefix (in-place Tc -> S)
  state_prefix_kernel<<<512, 256, 0, stream>>>(la_buf, Tc_buf);
  // 5c. Y_state apply (vectorized MFMA + LDS-bounced 16B RMW)
  ystate_kernel<<<2048, 256, 0, stream>>>(xbc_conv, Tc_buf, la_buf, y2);
  // 6. combine + gated rmsnorm
  combine_kernel<<<NROWS, 256, 0, stream>>>(y2, xbc_conv, out_z, Dp, norm_w, yn);
  // 7. m = yn @ W_out
  gemm_kernel<0><<<dim3(4, 128), 256, 0, stream>>>(yn, wt_out, NROWS, 512, 1024,
                                                   out_m, nullptr, nullptr, nullptr, nullptr, nullptr);
  // 8. h = rmsnorm(2m)
  rmsnorm2_kernel<<<NROWS, 256, 0, stream>>>(out_m, h_bf);
  // 9. g = gelu(h @ W1 + b1)
  gemm_kernel<2><<<dim3(16, 128), 256, 0, stream>>>(h_bf, w1t, NROWS, D_FF, 512,
                                                    nullptr, nullptr, nullptr, gelu_bf, b1, nullptr);
  // 10. x = 2m + g @ W2 + b2
  gemm_kernel<3><<<dim3(4, 128), 256, 0, stream>>>(gelu_bf, w2t, NROWS, 512, D_FF,
                                                   out_x, nullptr, nullptr, nullptr, b2, out_m);
}